// Round 14
// baseline (86.129 us; speedup 1.0000x reference)
//
#include <hip/hip_runtime.h>
#include <math.h>

static constexpr int B_  = 4;
static constexpr int TQ  = 128;
static constexpr int TK  = 512;
static constexpr int NN  = 1024;
static constexpr int QS  = 1024;
static constexpr int VS  = 1024;
static constexpr int OS  = 1024;

#define K2F    2.8853900817779268f   // 2*log2(e)
#define LOG2EF 1.4426950408889634f
#define SLICE  524288                // 512*1024

typedef __attribute__((ext_vector_type(8))) short bf16x8;
typedef __attribute__((ext_vector_type(4))) float f32x4;

#define MFMA16(a,b,c) __builtin_amdgcn_mfma_f32_16x16x32_bf16((a),(b),(c),0,0,0)

__device__ __forceinline__ ushort bf16_rne(float x) {
    uint u = __float_as_uint(x);
    u += 0x7FFFu + ((u >> 16) & 1u);
    return (ushort)(u >> 16);
}
__device__ __forceinline__ void split2(float x, ushort& h, ushort& l) {
    ushort hh = bf16_rne(x);
    float hv = __uint_as_float((uint)hh << 16);
    h = hh;
    l = bf16_rne(x - hv);
}

// ---------------------------------------------------------------------------
// [1] unified conversion: Q / Wq -> hi/lo, Wout -> hi, V transpose -> hi only
// ---------------------------------------------------------------------------
__global__ __launch_bounds__(256) void cvt_all_kernel(
    const float* __restrict__ Q, const float* __restrict__ Wq,
    const float* __restrict__ Wo, const float* __restrict__ V,
    ushort* __restrict__ Qh, ushort* __restrict__ Ql,
    ushort* __restrict__ Wqh, ushort* __restrict__ Wql,
    ushort* __restrict__ Woh,
    ushort* __restrict__ Vth)
{
    __shared__ float tile[64][65];
    const int bid = blockIdx.x;
    const int t = threadIdx.x;
    if (bid < 3584) {
        if (bid < 1536) {
            const float* src; ushort *h, *l; int idx;
            if (bid < 512) { src = Q;  h = Qh;  l = Ql;  idx = bid*256 + t; }
            else           { src = Wq; h = Wqh; l = Wql; idx = (bid-512)*256 + t; }
            float4 v = ((const float4*)src)[idx];
            ushort4 hh, ll;
            split2(v.x, hh.x, ll.x); split2(v.y, hh.y, ll.y);
            split2(v.z, hh.z, ll.z); split2(v.w, hh.w, ll.w);
            ((ushort4*)h)[idx] = hh;
            ((ushort4*)l)[idx] = ll;
        } else {
            int idx = (bid-1536)*256 + t;
            float4 v = ((const float4*)Wo)[idx];
            ushort4 hh;
            hh.x = bf16_rne(v.x); hh.y = bf16_rne(v.y);
            hh.z = bf16_rne(v.z); hh.w = bf16_rne(v.w);
            ((ushort4*)Woh)[idx] = hh;
        }
        return;
    }
    const int vid = bid - 3584;
    const int v0 = (vid & 15) * 64;
    const int k0 = ((vid >> 4) & 7) * 64;
    const int b  = vid >> 7;
    const float* src = V + ((size_t)b*TK + k0)*VS + v0;
    #pragma unroll
    for (int p = 0; p < 4; ++p) {
        int r = (t >> 4) + p*16, c = (t & 15) * 4;
        float4 vv = *(const float4*)(src + (size_t)r*VS + c);
        tile[r][c] = vv.x; tile[r][c+1] = vv.y; tile[r][c+2] = vv.z; tile[r][c+3] = vv.w;
    }
    __syncthreads();
    ushort* dh = Vth + (size_t)b*(VS*TK) + (size_t)v0*TK + k0;
    #pragma unroll
    for (int p = 0; p < 4; ++p) {
        int vr = (t >> 4) + p*16, kc = (t & 15) * 4;
        ushort4 hh;
        hh.x = bf16_rne(tile[kc+0][vr]);
        hh.y = bf16_rne(tile[kc+1][vr]);
        hh.z = bf16_rne(tile[kc+2][vr]);
        hh.w = bf16_rne(tile[kc+3][vr]);
        *(ushort4*)(dh + (size_t)vr*TK + kc) = hh;
    }
}

// ---------------------------------------------------------------------------
// [2] split-bf16 NT MFMA GEMM (3-MFMA, A+B hi/lo), M=512; A-GEMM.
// ---------------------------------------------------------------------------
__global__ __launch_bounds__(256) void mfma_nt_kernel(
    const ushort* __restrict__ Ah, const ushort* __restrict__ Al,
    const ushort* __restrict__ Bh, const ushort* __restrict__ Bl,
    float* __restrict__ Cp, int lda, int ldb, int Nout, int kchunk, int bstride)
{
    __shared__ alignas(16) ushort lA[2][64][40];
    __shared__ alignas(16) ushort lB[2][64][40];
    const int t = threadIdx.x;
    const int m0 = blockIdx.y * 64, n0 = blockIdx.x * 64, kz = blockIdx.z;
    const int k0 = kz * kchunk;
    const int batch = m0 >> 7;
    const ushort* bhp = Bh + (size_t)batch * bstride;
    const ushort* blp = Bl + (size_t)batch * bstride;
    const int srow = t >> 2, skc = (t & 3) * 8;
    const int lane = t & 63, w = t >> 6;
    const int wm = (w >> 1) * 32, wn = (w & 1) * 32;
    const int fr = lane & 15, fg = (lane >> 4) * 8;

    f32x4 acc00 = {0,0,0,0}, acc01 = {0,0,0,0}, acc10 = {0,0,0,0}, acc11 = {0,0,0,0};

    for (int kb = k0; kb < k0 + kchunk; kb += 32) {
        uint4 va_h = *(const uint4*)(Ah  + (size_t)(m0+srow)*lda + kb + skc);
        uint4 va_l = *(const uint4*)(Al  + (size_t)(m0+srow)*lda + kb + skc);
        uint4 vb_h = *(const uint4*)(bhp + (size_t)(n0+srow)*ldb + kb + skc);
        uint4 vb_l = *(const uint4*)(blp + (size_t)(n0+srow)*ldb + kb + skc);
        *(uint4*)&lA[0][srow][skc] = va_h;
        *(uint4*)&lA[1][srow][skc] = va_l;
        *(uint4*)&lB[0][srow][skc] = vb_h;
        *(uint4*)&lB[1][srow][skc] = vb_l;
        __syncthreads();
        bf16x8 ah0 = *(const bf16x8*)&lA[0][wm + fr     ][fg];
        bf16x8 ah1 = *(const bf16x8*)&lA[0][wm + 16 + fr][fg];
        bf16x8 al0 = *(const bf16x8*)&lA[1][wm + fr     ][fg];
        bf16x8 al1 = *(const bf16x8*)&lA[1][wm + 16 + fr][fg];
        bf16x8 bh0 = *(const bf16x8*)&lB[0][wn + fr     ][fg];
        bf16x8 bh1 = *(const bf16x8*)&lB[0][wn + 16 + fr][fg];
        bf16x8 bl0 = *(const bf16x8*)&lB[1][wn + fr     ][fg];
        bf16x8 bl1 = *(const bf16x8*)&lB[1][wn + 16 + fr][fg];
        acc00 = MFMA16(ah0, bh0, acc00);
        acc00 = MFMA16(al0, bh0, acc00);
        acc00 = MFMA16(ah0, bl0, acc00);
        acc01 = MFMA16(ah0, bh1, acc01);
        acc01 = MFMA16(al0, bh1, acc01);
        acc01 = MFMA16(ah0, bl1, acc01);
        acc10 = MFMA16(ah1, bh0, acc10);
        acc10 = MFMA16(al1, bh0, acc10);
        acc10 = MFMA16(ah1, bl0, acc10);
        acc11 = MFMA16(ah1, bh1, acc11);
        acc11 = MFMA16(al1, bh1, acc11);
        acc11 = MFMA16(ah1, bl1, acc11);
        __syncthreads();
    }
    float* o = Cp + (size_t)kz * 512 * Nout;
    const int orow = (lane >> 4) * 4;
    #pragma unroll
    for (int r2 = 0; r2 < 4; ++r2) {
        o[(size_t)(m0+wm+orow+r2)*Nout      + n0+wn+fr]      = acc00[r2];
        o[(size_t)(m0+wm+orow+r2)*Nout      + n0+wn+16+fr]   = acc01[r2];
        o[(size_t)(m0+wm+16+orow+r2)*Nout   + n0+wn+fr]      = acc10[r2];
        o[(size_t)(m0+wm+16+orow+r2)*Nout   + n0+wn+16+fr]   = acc11[r2];
    }
}

// ---------------------------------------------------------------------------
// [6] 2-MFMA NT GEMM (A hi/lo, B hi only), M=512. PV.
// ---------------------------------------------------------------------------
__global__ __launch_bounds__(256) void mfma_nt2_kernel(
    const ushort* __restrict__ Ah, const ushort* __restrict__ Al,
    const ushort* __restrict__ Bh,
    float* __restrict__ Cp, int lda, int ldb, int Nout, int kchunk, int bstride)
{
    __shared__ alignas(16) ushort lA[2][64][40];
    __shared__ alignas(16) ushort lB[64][40];
    const int t = threadIdx.x;
    const int m0 = blockIdx.y * 64, n0 = blockIdx.x * 64, kz = blockIdx.z;
    const int k0 = kz * kchunk;
    const int batch = m0 >> 7;
    const ushort* bhp = Bh + (size_t)batch * bstride;
    const int srow = t >> 2, skc = (t & 3) * 8;
    const int lane = t & 63, w = t >> 6;
    const int wm = (w >> 1) * 32, wn = (w & 1) * 32;
    const int fr = lane & 15, fg = (lane >> 4) * 8;

    f32x4 acc00 = {0,0,0,0}, acc01 = {0,0,0,0}, acc10 = {0,0,0,0}, acc11 = {0,0,0,0};

    for (int kb = k0; kb < k0 + kchunk; kb += 32) {
        *(uint4*)&lA[0][srow][skc] = *(const uint4*)(Ah  + (size_t)(m0+srow)*lda + kb + skc);
        *(uint4*)&lA[1][srow][skc] = *(const uint4*)(Al  + (size_t)(m0+srow)*lda + kb + skc);
        *(uint4*)&lB[srow][skc]    = *(const uint4*)(bhp + (size_t)(n0+srow)*ldb + kb + skc);
        __syncthreads();
        bf16x8 ah0 = *(const bf16x8*)&lA[0][wm + fr     ][fg];
        bf16x8 ah1 = *(const bf16x8*)&lA[0][wm + 16 + fr][fg];
        bf16x8 al0 = *(const bf16x8*)&lA[1][wm + fr     ][fg];
        bf16x8 al1 = *(const bf16x8*)&lA[1][wm + 16 + fr][fg];
        bf16x8 bh0 = *(const bf16x8*)&lB[wn + fr     ][fg];
        bf16x8 bh1 = *(const bf16x8*)&lB[wn + 16 + fr][fg];
        acc00 = MFMA16(ah0, bh0, acc00);
        acc00 = MFMA16(al0, bh0, acc00);
        acc01 = MFMA16(ah0, bh1, acc01);
        acc01 = MFMA16(al0, bh1, acc01);
        acc10 = MFMA16(ah1, bh0, acc10);
        acc10 = MFMA16(al1, bh0, acc10);
        acc11 = MFMA16(ah1, bh1, acc11);
        acc11 = MFMA16(al1, bh1, acc11);
        __syncthreads();
    }
    float* o = Cp + (size_t)kz * 512 * Nout;
    const int orow = (lane >> 4) * 4;
    #pragma unroll
    for (int r2 = 0; r2 < 4; ++r2) {
        o[(size_t)(m0+wm+orow+r2)*Nout      + n0+wn+fr]      = acc00[r2];
        o[(size_t)(m0+wm+orow+r2)*Nout      + n0+wn+16+fr]   = acc01[r2];
        o[(size_t)(m0+wm+16+orow+r2)*Nout   + n0+wn+fr]      = acc10[r2];
        o[(size_t)(m0+wm+16+orow+r2)*Nout   + n0+wn+16+fr]   = acc11[r2];
    }
}

// ---------------------------------------------------------------------------
// [3] Ea = exp2((sum of 4 Ap slices + bq) * K2F)
// ---------------------------------------------------------------------------
__global__ __launch_bounds__(256) void exp_combine_kernel(
    const float* __restrict__ Ap, const float* __restrict__ bias,
    float* __restrict__ E)
{
    int i = blockIdx.x * 256 + threadIdx.x;
    float4 p0 = ((const float4*)Ap)[i];
    float4 p1 = ((const float4*)(Ap + SLICE))[i];
    float4 p2 = ((const float4*)(Ap + 2*SLICE))[i];
    float4 p3 = ((const float4*)(Ap + 3*SLICE))[i];
    float4 bb = ((const float4*)bias)[i & 255];
    float4 r;
    r.x = exp2f((p0.x+p1.x+p2.x+p3.x+bb.x) * K2F);
    r.y = exp2f((p0.y+p1.y+p2.y+p3.y+bb.y) * K2F);
    r.z = exp2f((p0.z+p1.z+p2.z+p3.z+bb.z) * K2F);
    r.w = exp2f((p0.w+p1.w+p2.w+p3.w+bb.w) * K2F);
    ((float4*)E)[i] = r;
}

// ---------------------------------------------------------------------------
// [4] scores v10: 64q x 128k x 64n per block, 4q x 8k per thread (32 acc),
// 256 threads, grid 4kt x 8qt x 16nh = 512 blocks. 1.5 B LDS per eval ->
// VALU-bound by design; 32 independent acc chains give the ILP.
// ---------------------------------------------------------------------------
__global__ __launch_bounds__(256, 2) void score_v10_kernel(
    const float* __restrict__ Ea,   // [512][1024]
    const float* __restrict__ keys,
    const float* __restrict__ watt,
    float* __restrict__ Sp)         // [16][512][512]
{
    __shared__ float ea[64][66];    // [n][q]   16.9 KB
    __shared__ float ek[64][132];   // [n][k]   33.8 KB
    __shared__ float wl[64];
    const int tid = threadIdx.x;
    const int kt = blockIdx.x;      // 0..3  (128-k tiles)
    const int qt = blockIdx.y;      // 0..7  (64-q tiles)
    const int nh = blockIdx.z;      // 0..15
    const int nbeg = nh * 64;
    const int q0 = qt * 64;
    const int b  = qt >> 1;
    const int k0 = b*TK + kt*128;

    {   // stage ea[n][q]: thread q = tid>>2 (0..63), 16 n's
        const int q = tid >> 2;
        const int nc = (tid & 3) * 16;
        const float* ep = Ea + (size_t)(q0 + q)*NN + nbeg + nc;
        #pragma unroll
        for (int j4 = 0; j4 < 4; ++j4) {
            float4 ev = *(const float4*)(ep + j4*4);
            ea[nc+j4*4+0][q] = ev.x;
            ea[nc+j4*4+1][q] = ev.y;
            ea[nc+j4*4+2][q] = ev.z;
            ea[nc+j4*4+3][q] = ev.w;
        }
    }
    {   // stage ek[n][k] with exp2: thread k = tid>>1 (0..127), 32 n's
        const int k = tid >> 1;
        const int nc = (tid & 1) * 32;
        const float* kp = keys + (size_t)(k0 + k)*NN + nbeg + nc;
        #pragma unroll
        for (int j4 = 0; j4 < 8; ++j4) {
            float4 kv = *(const float4*)(kp + j4*4);
            ek[nc+j4*4+0][k] = exp2f(kv.x * K2F);
            ek[nc+j4*4+1][k] = exp2f(kv.y * K2F);
            ek[nc+j4*4+2][k] = exp2f(kv.z * K2F);
            ek[nc+j4*4+3][k] = exp2f(kv.w * K2F);
        }
    }
    if (tid < 64) wl[tid] = watt[nbeg + tid];
    __syncthreads();

    const int tx = tid & 15;        // k sub-tile (x8): 0..15
    const int ty = tid >> 4;        // q sub-tile (x4): 0..15
    float acc[4][8] = {};
    #pragma unroll 2
    for (int g = 0; g < 16; ++g) {
        float4 e0 = *(const float4*)&ea[4*g+0][ty*4];
        float4 e1 = *(const float4*)&ea[4*g+1][ty*4];
        float4 e2 = *(const float4*)&ea[4*g+2][ty*4];
        float4 e3 = *(const float4*)&ea[4*g+3][ty*4];
        float4 f0a = *(const float4*)&ek[4*g+0][tx*8];
        float4 f0b = *(const float4*)&ek[4*g+0][tx*8+4];
        float4 f1a = *(const float4*)&ek[4*g+1][tx*8];
        float4 f1b = *(const float4*)&ek[4*g+1][tx*8+4];
        float4 f2a = *(const float4*)&ek[4*g+2][tx*8];
        float4 f2b = *(const float4*)&ek[4*g+2][tx*8+4];
        float4 f3a = *(const float4*)&ek[4*g+3][tx*8];
        float4 f3b = *(const float4*)&ek[4*g+3][tx*8+4];
        float4 w4 = *(const float4*)&wl[4*g];
        float E0[4] = {e0.x,e0.y,e0.z,e0.w};
        float E1[4] = {e1.x,e1.y,e1.z,e1.w};
        float E2[4] = {e2.x,e2.y,e2.z,e2.w};
        float E3[4] = {e3.x,e3.y,e3.z,e3.w};
        float F0[8] = {f0a.x,f0a.y,f0a.z,f0a.w, f0b.x,f0b.y,f0b.z,f0b.w};
        float F1[8] = {f1a.x,f1a.y,f1a.z,f1a.w, f1b.x,f1b.y,f1b.z,f1b.w};
        float F2[8] = {f2a.x,f2a.y,f2a.z,f2a.w, f2b.x,f2b.y,f2b.z,f2b.w};
        float F3[8] = {f3a.x,f3a.y,f3a.z,f3a.w, f3b.x,f3b.y,f3b.z,f3b.w};
        #pragma unroll
        for (int i = 0; i < 4; ++i) {
            #pragma unroll
            for (int j = 0; j < 8; ++j) {
                float A  = fmaf(E0[i], F0[j], 1.0f);
                float Bv = fmaf(E1[i], F1[j], 1.0f);
                float C  = fmaf(E2[i], F2[j], 1.0f);
                float D  = fmaf(E3[i], F3[j], 1.0f);
                float n0 = fmaf(w4.x, Bv, w4.y * A);
                float n1 = fmaf(w4.z, D,  w4.w * C);
                acc[i][j] = fmaf(n0, __builtin_amdgcn_rcpf(A * Bv), acc[i][j]);
                acc[i][j] = fmaf(n1, __builtin_amdgcn_rcpf(C * D),  acc[i][j]);
            }
        }
    }
    float* o = Sp + ((size_t)nh*512 + q0 + ty*4)*TK + kt*128 + tx*8;
    #pragma unroll
    for (int i = 0; i < 4; ++i) {
        float4 r0 = {-2.0f*acc[i][0], -2.0f*acc[i][1], -2.0f*acc[i][2], -2.0f*acc[i][3]};
        float4 r1 = {-2.0f*acc[i][4], -2.0f*acc[i][5], -2.0f*acc[i][6], -2.0f*acc[i][7]};
        *(float4*)(o + (size_t)i*TK)     = r0;
        *(float4*)(o + (size_t)i*TK + 4) = r1;
    }
}

// ---------------------------------------------------------------------------
// [5] softmax over k of sum_{h<16} Sp[h]; P f32 + Ph/Pl
// ---------------------------------------------------------------------------
__global__ __launch_bounds__(256) void softmax_kernel(
    const float* __restrict__ Sp, float* __restrict__ P,
    ushort* __restrict__ Ph, ushort* __restrict__ Pl)
{
    const int lane = threadIdx.x & 63;
    const int wid  = threadIdx.x >> 6;
    const int row  = blockIdx.x * 4 + wid;
    const size_t S = (size_t)512*512;
    float v[8];
    float m = -3.4e38f;
    #pragma unroll
    for (int j = 0; j < 8; ++j) {
        int k = lane + j*64;
        float s = 0.f;
        #pragma unroll
        for (int h = 0; h < 16; ++h)
            s += Sp[h*S + (size_t)row*TK + k];
        v[j] = s;
        m = fmaxf(m, v[j]);
    }
    #pragma unroll
    for (int off = 32; off; off >>= 1) m = fmaxf(m, __shfl_xor(m, off, 64));
    float sum = 0.f;
    #pragma unroll
    for (int j = 0; j < 8; ++j) { v[j] = exp2f((v[j] - m) * LOG2EF); sum += v[j]; }
    #pragma unroll
    for (int off = 32; off; off >>= 1) sum += __shfl_xor(sum, off, 64);
    float inv = 1.0f / sum;
    #pragma unroll
    for (int j = 0; j < 8; ++j) {
        int k = lane + j*64;
        float pv = v[j] * inv;
        P[(size_t)row * TK + k] = pv;
        ushort h, l; split2(pv, h, l);
        Ph[(size_t)row * TK + k] = h;
        Pl[(size_t)row * TK + k] = l;
    }
}

// ---------------------------------------------------------------------------
// [7] Cx = sum of 4 Ep slices -> hi/lo bf16
// ---------------------------------------------------------------------------
__global__ __launch_bounds__(256) void combine_cvt_kernel(
    const float* __restrict__ Ep, ushort* __restrict__ Ch, ushort* __restrict__ Cl)
{
    int i = blockIdx.x * 256 + threadIdx.x;
    float4 p0 = ((const float4*)Ep)[i];
    float4 p1 = ((const float4*)(Ep + SLICE))[i];
    float4 p2 = ((const float4*)(Ep + 2*SLICE))[i];
    float4 p3 = ((const float4*)(Ep + 3*SLICE))[i];
    float4 s = {p0.x+p1.x+p2.x+p3.x, p0.y+p1.y+p2.y+p3.y,
                p0.z+p1.z+p2.z+p3.z, p0.w+p1.w+p2.w+p3.w};
    ushort4 hh, ll;
    split2(s.x, hh.x, ll.x); split2(s.y, hh.y, ll.y);
    split2(s.z, hh.z, ll.z); split2(s.w, hh.w, ll.w);
    ((ushort4*)Ch)[i] = hh;
    ((ushort4*)Cl)[i] = ll;
}

// ---------------------------------------------------------------------------
// [8] out-GEMM: A = [Q hi/lo | Cx hi/lo], B = Woh only (2-MFMA). K=2048/4.
// ---------------------------------------------------------------------------
__global__ __launch_bounds__(256) void mfma_out_kernel(
    const ushort* __restrict__ Qh, const ushort* __restrict__ Ql,
    const ushort* __restrict__ Cxh, const ushort* __restrict__ Cxl,
    const ushort* __restrict__ Wh,  // [1024][2048] hi
    float* __restrict__ Fp)
{
    __shared__ alignas(16) ushort lA[2][64][40];
    __shared__ alignas(16) ushort lB[64][40];
    const int t = threadIdx.x;
    const int m0 = blockIdx.y * 64, n0 = blockIdx.x * 64, kz = blockIdx.z;
    const ushort* ah_p = (kz < 2) ? Qh : Cxh;
    const ushort* al_p = (kz < 2) ? Ql : Cxl;
    const int akoff = (kz & 1) * 512;
    const int bkoff = kz * 512;
    const int srow = t >> 2, skc = (t & 3) * 8;
    const int lane = t & 63, w = t >> 6;
    const int wm = (w >> 1) * 32, wn = (w & 1) * 32;
    const int fr = lane & 15, fg = (lane >> 4) * 8;

    f32x4 acc00 = {0,0,0,0}, acc01 = {0,0,0,0}, acc10 = {0,0,0,0}, acc11 = {0,0,0,0};

    for (int kk = 0; kk < 512; kk += 32) {
        size_t aoff = (size_t)(m0+srow)*1024 + akoff + kk + skc;
        *(uint4*)&lA[0][srow][skc] = *(const uint4*)(ah_p + aoff);
        *(uint4*)&lA[1][srow][skc] = *(const uint4*)(al_p + aoff);
        *(uint4*)&lB[srow][skc] =
            *(const uint4*)(Wh + (size_t)(n0+srow)*2048 + bkoff + kk + skc);
        __syncthreads();
        bf16x8 ah0 = *(const bf16x8*)&lA[0][wm + fr     ][fg];
        bf16x8 ah1 = *(const bf16x8*)&lA[0][wm + 16 + fr][fg];
        bf16x8 al0 = *(const bf16x8*)&lA[1][wm + fr     ][fg];
        bf16x8 al1 = *(const bf16x8*)&lA[1][wm + 16 + fr][fg];
        bf16x8 bh0 = *(const bf16x8*)&lB[wn + fr     ][fg];
        bf16x8 bh1 = *(const bf16x8*)&lB[wn + 16 + fr][fg];
        acc00 = MFMA16(ah0, bh0, acc00);
        acc00 = MFMA16(al0, bh0, acc00);
        acc01 = MFMA16(ah0, bh1, acc01);
        acc01 = MFMA16(al0, bh1, acc01);
        acc10 = MFMA16(ah1, bh0, acc10);
        acc10 = MFMA16(al1, bh0, acc10);
        acc11 = MFMA16(ah1, bh1, acc11);
        acc11 = MFMA16(al1, bh1, acc11);
        __syncthreads();
    }
    float* o = Fp + (size_t)kz * SLICE;
    const int orow = (lane >> 4) * 4;
    #pragma unroll
    for (int r2 = 0; r2 < 4; ++r2) {
        o[(size_t)(m0+wm+orow+r2)*1024    + n0+wn+fr]    = acc00[r2];
        o[(size_t)(m0+wm+orow+r2)*1024    + n0+wn+16+fr] = acc01[r2];
        o[(size_t)(m0+wm+16+orow+r2)*1024 + n0+wn+fr]    = acc10[r2];
        o[(size_t)(m0+wm+16+orow+r2)*1024 + n0+wn+16+fr] = acc11[r2];
    }
}

// ---------------------------------------------------------------------------
// [9] out = tanh(sum Fp + bias)
// ---------------------------------------------------------------------------
__global__ __launch_bounds__(256) void tanh_combine_kernel(
    const float* __restrict__ Fp, const float* __restrict__ bias,
    float* __restrict__ out)
{
    int i = blockIdx.x * 256 + threadIdx.x;
    const size_t S = (size_t)B_*TQ*OS;
    float4 p0 = ((const float4*)Fp)[i];
    float4 p1 = ((const float4*)(Fp + S))[i];
    float4 p2 = ((const float4*)(Fp + 2*S))[i];
    float4 p3 = ((const float4*)(Fp + 3*S))[i];
    float4 bb = ((const float4*)bias)[i & 255];
    float4 r;
    r.x = tanhf(p0.x + p1.x + p2.x + p3.x + bb.x);
    r.y = tanhf(p0.y + p1.y + p2.y + p3.y + bb.y);
    r.z = tanhf(p0.z + p1.z + p2.z + p3.z + bb.z);
    r.w = tanhf(p0.w + p1.w + p2.w + p3.w + bb.w);
    ((float4*)out)[i] = r;
}

// ---------------------------------------------------------------------------
extern "C" void kernel_launch(void* const* d_in, const int* in_sizes, int n_in,
                              void* d_out, int out_size, void* d_ws, size_t ws_size,
                              hipStream_t stream)
{
    const float* query  = (const float*)d_in[0];
    const float* keys   = (const float*)d_in[1];
    const float* values = (const float*)d_in[2];
    const float* Wq     = (const float*)d_in[3];
    const float* bq     = (const float*)d_in[4];
    const float* watt   = (const float*)d_in[5];
    // d_in[6] = b_att: dropped (softmax shift-invariance)
    const float* Wout   = (const float*)d_in[7];
    const float* bout   = (const float*)d_in[8];

    float* out = (float*)d_out;                    // output 0 (524288 f32)
    float* P   = out + (size_t)B_*TQ*OS;           // output 1 (262144 f32)

    char* base = (char*)d_ws;
    const size_t MB = 1u << 20;
    ushort* Qh  = (ushort*)(base +  0*MB);
    ushort* Ql  = (ushort*)(base +  1*MB);
    ushort* Wqh = (ushort*)(base +  2*MB);
    ushort* Wql = (ushort*)(base +  4*MB);
    ushort* Woh = (ushort*)(base +  6*MB);   // 4 MB (hi only)
    ushort* Vth = (ushort*)(base + 10*MB);   // 4 MB (hi only)
    float*  Ap  = (float*) (base + 14*MB);   // [4][512][1024] = 8 MB
    float*  Ea  = (float*) (base + 22*MB);   // 2 MB
    float*  Sp  = (float*) (base + 24*MB);   // [16][512][512] = 16 MB
    ushort* Ph  = (ushort*)(base + 40*MB);
    ushort* Pl  = (ushort*)(base + 40*MB + 512*1024);
    float*  Ep  = (float*) (base + 41*MB);   // [4][512][1024] = 8 MB
    ushort* Cxh = (ushort*)(base + 49*MB);
    ushort* Cxl = (ushort*)(base + 50*MB);
    float*  Fp  = (float*) (base + 51*MB);   // [4][512][1024] = 8 MB

    // [1] conversions + V transpose (hi only)
    cvt_all_kernel<<<dim3(4096), dim3(256), 0, stream>>>(
        query, Wq, Wout, values, Qh, Ql, Wqh, Wql, Woh, Vth);
    // [2] A-GEMM partials: Q @ Wq^T (3-MFMA, K=1024 split 4)
    mfma_nt_kernel<<<dim3(16, 8, 4), dim3(256), 0, stream>>>(
        Qh, Ql, Wqh, Wql, Ap, 1024, 1024, 1024, 256, 0);
    // [3] Ea = exp(2*(sum Ap + bq))
    exp_combine_kernel<<<dim3(512), dim3(256), 0, stream>>>(Ap, bq, Ea);
    // [4] scores v10 (4q x 8k register tile; 1.5 B LDS per eval)
    score_v10_kernel<<<dim3(4, 8, 16), dim3(256), 0, stream>>>(Ea, keys, watt, Sp);
    // [5] softmax -> P (output 1) + Ph/Pl
    softmax_kernel<<<dim3(128), dim3(256), 0, stream>>>(Sp, P, Ph, Pl);
    // [6] PV partials: P @ V (2-MFMA, per-batch, K=512 split 4)
    mfma_nt2_kernel<<<dim3(16, 8, 4), dim3(256), 0, stream>>>(
        Ph, Pl, Vth, Ep, 512, 512, 1024, 128, VS*TK);
    // [7] Cx = sum Ep -> hi/lo bf16
    combine_cvt_kernel<<<dim3(512), dim3(256), 0, stream>>>(Ep, Cxh, Cxl);
    // [8] out-GEMM partials (2-MFMA, B hi only; K=2048 split 4)
    mfma_out_kernel<<<dim3(16, 8, 4), dim3(256), 0, stream>>>(
        Qh, Ql, Cxh, Cxl, Woh, Fp);
    // [9] out = tanh(sum + bout)
    tanh_combine_kernel<<<dim3(512), dim3(256), 0, stream>>>(Fp, bout, out);
}

// Round 15
// 85.075 us; speedup vs baseline: 1.0124x; 1.0124x over previous
//
#include <hip/hip_runtime.h>
#include <math.h>

static constexpr int B_  = 4;
static constexpr int TQ  = 128;
static constexpr int TK  = 512;
static constexpr int NN  = 1024;
static constexpr int QS  = 1024;
static constexpr int VS  = 1024;
static constexpr int OS  = 1024;

#define K2F    2.8853900817779268f   // 2*log2(e)
#define LOG2EF 1.4426950408889634f
#define SLICE  524288                // 512*1024

typedef __attribute__((ext_vector_type(8))) short bf16x8;
typedef __attribute__((ext_vector_type(4))) float f32x4;

#define MFMA16(a,b,c) __builtin_amdgcn_mfma_f32_16x16x32_bf16((a),(b),(c),0,0,0)

__device__ __forceinline__ ushort bf16_rne(float x) {
    uint u = __float_as_uint(x);
    u += 0x7FFFu + ((u >> 16) & 1u);
    return (ushort)(u >> 16);
}
__device__ __forceinline__ void split2(float x, ushort& h, ushort& l) {
    ushort hh = bf16_rne(x);
    float hv = __uint_as_float((uint)hh << 16);
    h = hh;
    l = bf16_rne(x - hv);
}

// ---------------------------------------------------------------------------
// [1] unified conversion: Q / Wq -> hi/lo, Wout -> hi, V transpose -> hi only
// ---------------------------------------------------------------------------
__global__ __launch_bounds__(256) void cvt_all_kernel(
    const float* __restrict__ Q, const float* __restrict__ Wq,
    const float* __restrict__ Wo, const float* __restrict__ V,
    ushort* __restrict__ Qh, ushort* __restrict__ Ql,
    ushort* __restrict__ Wqh, ushort* __restrict__ Wql,
    ushort* __restrict__ Woh,
    ushort* __restrict__ Vth)
{
    __shared__ float tile[64][65];
    const int bid = blockIdx.x;
    const int t = threadIdx.x;
    if (bid < 3584) {
        if (bid < 1536) {
            const float* src; ushort *h, *l; int idx;
            if (bid < 512) { src = Q;  h = Qh;  l = Ql;  idx = bid*256 + t; }
            else           { src = Wq; h = Wqh; l = Wql; idx = (bid-512)*256 + t; }
            float4 v = ((const float4*)src)[idx];
            ushort4 hh, ll;
            split2(v.x, hh.x, ll.x); split2(v.y, hh.y, ll.y);
            split2(v.z, hh.z, ll.z); split2(v.w, hh.w, ll.w);
            ((ushort4*)h)[idx] = hh;
            ((ushort4*)l)[idx] = ll;
        } else {
            int idx = (bid-1536)*256 + t;
            float4 v = ((const float4*)Wo)[idx];
            ushort4 hh;
            hh.x = bf16_rne(v.x); hh.y = bf16_rne(v.y);
            hh.z = bf16_rne(v.z); hh.w = bf16_rne(v.w);
            ((ushort4*)Woh)[idx] = hh;
        }
        return;
    }
    const int vid = bid - 3584;
    const int v0 = (vid & 15) * 64;
    const int k0 = ((vid >> 4) & 7) * 64;
    const int b  = vid >> 7;
    const float* src = V + ((size_t)b*TK + k0)*VS + v0;
    #pragma unroll
    for (int p = 0; p < 4; ++p) {
        int r = (t >> 4) + p*16, c = (t & 15) * 4;
        float4 vv = *(const float4*)(src + (size_t)r*VS + c);
        tile[r][c] = vv.x; tile[r][c+1] = vv.y; tile[r][c+2] = vv.z; tile[r][c+3] = vv.w;
    }
    __syncthreads();
    ushort* dh = Vth + (size_t)b*(VS*TK) + (size_t)v0*TK + k0;
    #pragma unroll
    for (int p = 0; p < 4; ++p) {
        int vr = (t >> 4) + p*16, kc = (t & 15) * 4;
        ushort4 hh;
        hh.x = bf16_rne(tile[kc+0][vr]);
        hh.y = bf16_rne(tile[kc+1][vr]);
        hh.z = bf16_rne(tile[kc+2][vr]);
        hh.w = bf16_rne(tile[kc+3][vr]);
        *(ushort4*)(dh + (size_t)vr*TK + kc) = hh;
    }
}

// ---------------------------------------------------------------------------
// [2] split-bf16 NT MFMA GEMM (3-MFMA, A+B hi/lo), M=512; A-GEMM. K-split 8.
// ---------------------------------------------------------------------------
__global__ __launch_bounds__(256) void mfma_nt_kernel(
    const ushort* __restrict__ Ah, const ushort* __restrict__ Al,
    const ushort* __restrict__ Bh, const ushort* __restrict__ Bl,
    float* __restrict__ Cp, int lda, int ldb, int Nout, int kchunk, int bstride)
{
    __shared__ alignas(16) ushort lA[2][64][40];
    __shared__ alignas(16) ushort lB[2][64][40];
    const int t = threadIdx.x;
    const int m0 = blockIdx.y * 64, n0 = blockIdx.x * 64, kz = blockIdx.z;
    const int k0 = kz * kchunk;
    const int batch = m0 >> 7;
    const ushort* bhp = Bh + (size_t)batch * bstride;
    const ushort* blp = Bl + (size_t)batch * bstride;
    const int srow = t >> 2, skc = (t & 3) * 8;
    const int lane = t & 63, w = t >> 6;
    const int wm = (w >> 1) * 32, wn = (w & 1) * 32;
    const int fr = lane & 15, fg = (lane >> 4) * 8;

    f32x4 acc00 = {0,0,0,0}, acc01 = {0,0,0,0}, acc10 = {0,0,0,0}, acc11 = {0,0,0,0};

    for (int kb = k0; kb < k0 + kchunk; kb += 32) {
        uint4 va_h = *(const uint4*)(Ah  + (size_t)(m0+srow)*lda + kb + skc);
        uint4 va_l = *(const uint4*)(Al  + (size_t)(m0+srow)*lda + kb + skc);
        uint4 vb_h = *(const uint4*)(bhp + (size_t)(n0+srow)*ldb + kb + skc);
        uint4 vb_l = *(const uint4*)(blp + (size_t)(n0+srow)*ldb + kb + skc);
        *(uint4*)&lA[0][srow][skc] = va_h;
        *(uint4*)&lA[1][srow][skc] = va_l;
        *(uint4*)&lB[0][srow][skc] = vb_h;
        *(uint4*)&lB[1][srow][skc] = vb_l;
        __syncthreads();
        bf16x8 ah0 = *(const bf16x8*)&lA[0][wm + fr     ][fg];
        bf16x8 ah1 = *(const bf16x8*)&lA[0][wm + 16 + fr][fg];
        bf16x8 al0 = *(const bf16x8*)&lA[1][wm + fr     ][fg];
        bf16x8 al1 = *(const bf16x8*)&lA[1][wm + 16 + fr][fg];
        bf16x8 bh0 = *(const bf16x8*)&lB[0][wn + fr     ][fg];
        bf16x8 bh1 = *(const bf16x8*)&lB[0][wn + 16 + fr][fg];
        bf16x8 bl0 = *(const bf16x8*)&lB[1][wn + fr     ][fg];
        bf16x8 bl1 = *(const bf16x8*)&lB[1][wn + 16 + fr][fg];
        acc00 = MFMA16(ah0, bh0, acc00);
        acc00 = MFMA16(al0, bh0, acc00);
        acc00 = MFMA16(ah0, bl0, acc00);
        acc01 = MFMA16(ah0, bh1, acc01);
        acc01 = MFMA16(al0, bh1, acc01);
        acc01 = MFMA16(ah0, bl1, acc01);
        acc10 = MFMA16(ah1, bh0, acc10);
        acc10 = MFMA16(al1, bh0, acc10);
        acc10 = MFMA16(ah1, bl0, acc10);
        acc11 = MFMA16(ah1, bh1, acc11);
        acc11 = MFMA16(al1, bh1, acc11);
        acc11 = MFMA16(ah1, bl1, acc11);
        __syncthreads();
    }
    float* o = Cp + (size_t)kz * 512 * Nout;
    const int orow = (lane >> 4) * 4;
    #pragma unroll
    for (int r2 = 0; r2 < 4; ++r2) {
        o[(size_t)(m0+wm+orow+r2)*Nout      + n0+wn+fr]      = acc00[r2];
        o[(size_t)(m0+wm+orow+r2)*Nout      + n0+wn+16+fr]   = acc01[r2];
        o[(size_t)(m0+wm+16+orow+r2)*Nout   + n0+wn+fr]      = acc10[r2];
        o[(size_t)(m0+wm+16+orow+r2)*Nout   + n0+wn+16+fr]   = acc11[r2];
    }
}

// ---------------------------------------------------------------------------
// [6] 2-MFMA NT GEMM (A hi/lo, B hi only), M=512. PV. K-split 8.
// ---------------------------------------------------------------------------
__global__ __launch_bounds__(256) void mfma_nt2_kernel(
    const ushort* __restrict__ Ah, const ushort* __restrict__ Al,
    const ushort* __restrict__ Bh,
    float* __restrict__ Cp, int lda, int ldb, int Nout, int kchunk, int bstride)
{
    __shared__ alignas(16) ushort lA[2][64][40];
    __shared__ alignas(16) ushort lB[64][40];
    const int t = threadIdx.x;
    const int m0 = blockIdx.y * 64, n0 = blockIdx.x * 64, kz = blockIdx.z;
    const int k0 = kz * kchunk;
    const int batch = m0 >> 7;
    const ushort* bhp = Bh + (size_t)batch * bstride;
    const int srow = t >> 2, skc = (t & 3) * 8;
    const int lane = t & 63, w = t >> 6;
    const int wm = (w >> 1) * 32, wn = (w & 1) * 32;
    const int fr = lane & 15, fg = (lane >> 4) * 8;

    f32x4 acc00 = {0,0,0,0}, acc01 = {0,0,0,0}, acc10 = {0,0,0,0}, acc11 = {0,0,0,0};

    for (int kb = k0; kb < k0 + kchunk; kb += 32) {
        *(uint4*)&lA[0][srow][skc] = *(const uint4*)(Ah  + (size_t)(m0+srow)*lda + kb + skc);
        *(uint4*)&lA[1][srow][skc] = *(const uint4*)(Al  + (size_t)(m0+srow)*lda + kb + skc);
        *(uint4*)&lB[srow][skc]    = *(const uint4*)(bhp + (size_t)(n0+srow)*ldb + kb + skc);
        __syncthreads();
        bf16x8 ah0 = *(const bf16x8*)&lA[0][wm + fr     ][fg];
        bf16x8 ah1 = *(const bf16x8*)&lA[0][wm + 16 + fr][fg];
        bf16x8 al0 = *(const bf16x8*)&lA[1][wm + fr     ][fg];
        bf16x8 al1 = *(const bf16x8*)&lA[1][wm + 16 + fr][fg];
        bf16x8 bh0 = *(const bf16x8*)&lB[wn + fr     ][fg];
        bf16x8 bh1 = *(const bf16x8*)&lB[wn + 16 + fr][fg];
        acc00 = MFMA16(ah0, bh0, acc00);
        acc00 = MFMA16(al0, bh0, acc00);
        acc01 = MFMA16(ah0, bh1, acc01);
        acc01 = MFMA16(al0, bh1, acc01);
        acc10 = MFMA16(ah1, bh0, acc10);
        acc10 = MFMA16(al1, bh0, acc10);
        acc11 = MFMA16(ah1, bh1, acc11);
        acc11 = MFMA16(al1, bh1, acc11);
        __syncthreads();
    }
    float* o = Cp + (size_t)kz * 512 * Nout;
    const int orow = (lane >> 4) * 4;
    #pragma unroll
    for (int r2 = 0; r2 < 4; ++r2) {
        o[(size_t)(m0+wm+orow+r2)*Nout      + n0+wn+fr]      = acc00[r2];
        o[(size_t)(m0+wm+orow+r2)*Nout      + n0+wn+16+fr]   = acc01[r2];
        o[(size_t)(m0+wm+16+orow+r2)*Nout   + n0+wn+fr]      = acc10[r2];
        o[(size_t)(m0+wm+16+orow+r2)*Nout   + n0+wn+16+fr]   = acc11[r2];
    }
}

// ---------------------------------------------------------------------------
// [3] Ea = exp2((sum of 8 Ap slices + bq) * K2F)
// ---------------------------------------------------------------------------
__global__ __launch_bounds__(256) void exp_combine_kernel(
    const float* __restrict__ Ap, const float* __restrict__ bias,
    float* __restrict__ E)
{
    int i = blockIdx.x * 256 + threadIdx.x;
    float s0 = 0.f, s1 = 0.f, s2 = 0.f, s3 = 0.f;
    #pragma unroll
    for (int h = 0; h < 8; ++h) {
        float4 p = ((const float4*)(Ap + (size_t)h*SLICE))[i];
        s0 += p.x; s1 += p.y; s2 += p.z; s3 += p.w;
    }
    float4 bb = ((const float4*)bias)[i & 255];
    float4 r;
    r.x = exp2f((s0 + bb.x) * K2F);
    r.y = exp2f((s1 + bb.y) * K2F);
    r.z = exp2f((s2 + bb.z) * K2F);
    r.w = exp2f((s3 + bb.w) * K2F);
    ((float4*)E)[i] = r;
}

// ---------------------------------------------------------------------------
// [4] scores v9: 512-thread blocks (8 waves), 64q x 64k x 64n tile,
// 2x4/thread, paired-rcp. Grid 8kt x 8qt x 16nh = 1024 blocks.
// ---------------------------------------------------------------------------
__global__ __launch_bounds__(512, 4) void score_v9_kernel(
    const float* __restrict__ Ea,   // [512][1024]
    const float* __restrict__ keys,
    const float* __restrict__ watt,
    float* __restrict__ Sp)         // [16][512][512]
{
    __shared__ float ea[64][66];
    __shared__ float ek[64][68];
    __shared__ float wl[64];
    const int tid = threadIdx.x;
    const int kt = blockIdx.x;      // 0..7
    const int qt = blockIdx.y;      // 0..7
    const int nh = blockIdx.z;      // 0..15
    const int nbeg = nh * 64;
    const int q0 = qt * 64;
    const int b  = qt >> 1;
    const int k0 = b*TK + kt*64;

    {   // stage ea[n][q]
        const int q = tid >> 3;
        const int nc = (tid & 7) * 8;
        const float* ep = Ea + (size_t)(q0 + q)*NN + nbeg + nc;
        float4 e0 = *(const float4*)(ep);
        float4 e1 = *(const float4*)(ep + 4);
        ea[nc+0][q] = e0.x; ea[nc+1][q] = e0.y; ea[nc+2][q] = e0.z; ea[nc+3][q] = e0.w;
        ea[nc+4][q] = e1.x; ea[nc+5][q] = e1.y; ea[nc+6][q] = e1.z; ea[nc+7][q] = e1.w;
    }
    {   // stage ek[n][k] with exp2
        const int k = tid >> 3;
        const int nc = (tid & 7) * 8;
        const float* kp = keys + (size_t)(k0 + k)*NN + nbeg + nc;
        float4 k0v = *(const float4*)(kp);
        float4 k1v = *(const float4*)(kp + 4);
        ek[nc+0][k] = exp2f(k0v.x * K2F);
        ek[nc+1][k] = exp2f(k0v.y * K2F);
        ek[nc+2][k] = exp2f(k0v.z * K2F);
        ek[nc+3][k] = exp2f(k0v.w * K2F);
        ek[nc+4][k] = exp2f(k1v.x * K2F);
        ek[nc+5][k] = exp2f(k1v.y * K2F);
        ek[nc+6][k] = exp2f(k1v.z * K2F);
        ek[nc+7][k] = exp2f(k1v.w * K2F);
    }
    if (tid < 64) wl[tid] = watt[nbeg + tid];
    __syncthreads();

    const int tx = tid & 15;
    const int ty = tid >> 4;
    float acc[2][4] = {};
    #pragma unroll 4
    for (int g = 0; g < 16; ++g) {
        float2 e0 = *(const float2*)&ea[4*g+0][ty*2];
        float2 e1 = *(const float2*)&ea[4*g+1][ty*2];
        float2 e2 = *(const float2*)&ea[4*g+2][ty*2];
        float2 e3 = *(const float2*)&ea[4*g+3][ty*2];
        float4 f0 = *(const float4*)&ek[4*g+0][tx*4];
        float4 f1 = *(const float4*)&ek[4*g+1][tx*4];
        float4 f2 = *(const float4*)&ek[4*g+2][tx*4];
        float4 f3 = *(const float4*)&ek[4*g+3][tx*4];
        float4 w4 = *(const float4*)&wl[4*g];
        float E0[2] = {e0.x, e0.y};
        float E1[2] = {e1.x, e1.y};
        float E2[2] = {e2.x, e2.y};
        float E3[2] = {e3.x, e3.y};
        float F0[4] = {f0.x, f0.y, f0.z, f0.w};
        float F1[4] = {f1.x, f1.y, f1.z, f1.w};
        float F2[4] = {f2.x, f2.y, f2.z, f2.w};
        float F3[4] = {f3.x, f3.y, f3.z, f3.w};
        #pragma unroll
        for (int i = 0; i < 2; ++i) {
            #pragma unroll
            for (int j = 0; j < 4; ++j) {
                float A  = fmaf(E0[i], F0[j], 1.0f);
                float Bv = fmaf(E1[i], F1[j], 1.0f);
                float C  = fmaf(E2[i], F2[j], 1.0f);
                float D  = fmaf(E3[i], F3[j], 1.0f);
                float n0 = fmaf(w4.x, Bv, w4.y * A);
                float n1 = fmaf(w4.z, D,  w4.w * C);
                acc[i][j] = fmaf(n0, __builtin_amdgcn_rcpf(A * Bv), acc[i][j]);
                acc[i][j] = fmaf(n1, __builtin_amdgcn_rcpf(C * D),  acc[i][j]);
            }
        }
    }
    float* o = Sp + ((size_t)nh*512 + q0 + ty*2)*TK + kt*64 + tx*4;
    #pragma unroll
    for (int i = 0; i < 2; ++i) {
        float4 r = {-2.0f*acc[i][0], -2.0f*acc[i][1], -2.0f*acc[i][2], -2.0f*acc[i][3]};
        *(float4*)(o + (size_t)i*TK) = r;
    }
}

// ---------------------------------------------------------------------------
// [5] softmax over k of sum_{h<16} Sp[h]; P f32 + Ph/Pl
// ---------------------------------------------------------------------------
__global__ __launch_bounds__(256) void softmax_kernel(
    const float* __restrict__ Sp, float* __restrict__ P,
    ushort* __restrict__ Ph, ushort* __restrict__ Pl)
{
    const int lane = threadIdx.x & 63;
    const int wid  = threadIdx.x >> 6;
    const int row  = blockIdx.x * 4 + wid;
    const size_t S = (size_t)512*512;
    float v[8];
    float m = -3.4e38f;
    #pragma unroll
    for (int j = 0; j < 8; ++j) {
        int k = lane + j*64;
        float s = 0.f;
        #pragma unroll
        for (int h = 0; h < 16; ++h)
            s += Sp[h*S + (size_t)row*TK + k];
        v[j] = s;
        m = fmaxf(m, v[j]);
    }
    #pragma unroll
    for (int off = 32; off; off >>= 1) m = fmaxf(m, __shfl_xor(m, off, 64));
    float sum = 0.f;
    #pragma unroll
    for (int j = 0; j < 8; ++j) { v[j] = exp2f((v[j] - m) * LOG2EF); sum += v[j]; }
    #pragma unroll
    for (int off = 32; off; off >>= 1) sum += __shfl_xor(sum, off, 64);
    float inv = 1.0f / sum;
    #pragma unroll
    for (int j = 0; j < 8; ++j) {
        int k = lane + j*64;
        float pv = v[j] * inv;
        P[(size_t)row * TK + k] = pv;
        ushort h, l; split2(pv, h, l);
        Ph[(size_t)row * TK + k] = h;
        Pl[(size_t)row * TK + k] = l;
    }
}

// ---------------------------------------------------------------------------
// [7] Cx = sum of 8 Ep slices -> hi/lo bf16
// ---------------------------------------------------------------------------
__global__ __launch_bounds__(256) void combine_cvt_kernel(
    const float* __restrict__ Ep, ushort* __restrict__ Ch, ushort* __restrict__ Cl)
{
    int i = blockIdx.x * 256 + threadIdx.x;
    float s0 = 0.f, s1 = 0.f, s2 = 0.f, s3 = 0.f;
    #pragma unroll
    for (int h = 0; h < 8; ++h) {
        float4 p = ((const float4*)(Ep + (size_t)h*SLICE))[i];
        s0 += p.x; s1 += p.y; s2 += p.z; s3 += p.w;
    }
    ushort4 hh, ll;
    split2(s0, hh.x, ll.x); split2(s1, hh.y, ll.y);
    split2(s2, hh.z, ll.z); split2(s3, hh.w, ll.w);
    ((ushort4*)Ch)[i] = hh;
    ((ushort4*)Cl)[i] = ll;
}

// ---------------------------------------------------------------------------
// [8] out-GEMM: A = [Q hi/lo | Cx hi/lo], B = Woh only (2-MFMA). K=2048/8.
// ---------------------------------------------------------------------------
__global__ __launch_bounds__(256) void mfma_out_kernel(
    const ushort* __restrict__ Qh, const ushort* __restrict__ Ql,
    const ushort* __restrict__ Cxh, const ushort* __restrict__ Cxl,
    const ushort* __restrict__ Wh,  // [1024][2048] hi
    float* __restrict__ Fp)
{
    __shared__ alignas(16) ushort lA[2][64][40];
    __shared__ alignas(16) ushort lB[64][40];
    const int t = threadIdx.x;
    const int m0 = blockIdx.y * 64, n0 = blockIdx.x * 64, kz = blockIdx.z;  // kz 0..7
    const ushort* ah_p = (kz < 4) ? Qh : Cxh;
    const ushort* al_p = (kz < 4) ? Ql : Cxl;
    const int akoff = (kz & 3) * 256;
    const int bkoff = kz * 256;
    const int srow = t >> 2, skc = (t & 3) * 8;
    const int lane = t & 63, w = t >> 6;
    const int wm = (w >> 1) * 32, wn = (w & 1) * 32;
    const int fr = lane & 15, fg = (lane >> 4) * 8;

    f32x4 acc00 = {0,0,0,0}, acc01 = {0,0,0,0}, acc10 = {0,0,0,0}, acc11 = {0,0,0,0};

    for (int kk = 0; kk < 256; kk += 32) {
        size_t aoff = (size_t)(m0+srow)*1024 + akoff + kk + skc;
        *(uint4*)&lA[0][srow][skc] = *(const uint4*)(ah_p + aoff);
        *(uint4*)&lA[1][srow][skc] = *(const uint4*)(al_p + aoff);
        *(uint4*)&lB[srow][skc] =
            *(const uint4*)(Wh + (size_t)(n0+srow)*2048 + bkoff + kk + skc);
        __syncthreads();
        bf16x8 ah0 = *(const bf16x8*)&lA[0][wm + fr     ][fg];
        bf16x8 ah1 = *(const bf16x8*)&lA[0][wm + 16 + fr][fg];
        bf16x8 al0 = *(const bf16x8*)&lA[1][wm + fr     ][fg];
        bf16x8 al1 = *(const bf16x8*)&lA[1][wm + 16 + fr][fg];
        bf16x8 bh0 = *(const bf16x8*)&lB[wn + fr     ][fg];
        bf16x8 bh1 = *(const bf16x8*)&lB[wn + 16 + fr][fg];
        acc00 = MFMA16(ah0, bh0, acc00);
        acc00 = MFMA16(al0, bh0, acc00);
        acc01 = MFMA16(ah0, bh1, acc01);
        acc01 = MFMA16(al0, bh1, acc01);
        acc10 = MFMA16(ah1, bh0, acc10);
        acc10 = MFMA16(al1, bh0, acc10);
        acc11 = MFMA16(ah1, bh1, acc11);
        acc11 = MFMA16(al1, bh1, acc11);
        __syncthreads();
    }
    float* o = Fp + (size_t)kz * SLICE;
    const int orow = (lane >> 4) * 4;
    #pragma unroll
    for (int r2 = 0; r2 < 4; ++r2) {
        o[(size_t)(m0+wm+orow+r2)*1024    + n0+wn+fr]    = acc00[r2];
        o[(size_t)(m0+wm+orow+r2)*1024    + n0+wn+16+fr] = acc01[r2];
        o[(size_t)(m0+wm+16+orow+r2)*1024 + n0+wn+fr]    = acc10[r2];
        o[(size_t)(m0+wm+16+orow+r2)*1024 + n0+wn+16+fr] = acc11[r2];
    }
}

// ---------------------------------------------------------------------------
// [9] out = tanh(sum of 8 Fp slices + bias)
// ---------------------------------------------------------------------------
__global__ __launch_bounds__(256) void tanh_combine_kernel(
    const float* __restrict__ Fp, const float* __restrict__ bias,
    float* __restrict__ out)
{
    int i = blockIdx.x * 256 + threadIdx.x;
    float s0 = 0.f, s1 = 0.f, s2 = 0.f, s3 = 0.f;
    #pragma unroll
    for (int h = 0; h < 8; ++h) {
        float4 p = ((const float4*)(Fp + (size_t)h*SLICE))[i];
        s0 += p.x; s1 += p.y; s2 += p.z; s3 += p.w;
    }
    float4 bb = ((const float4*)bias)[i & 255];
    float4 r;
    r.x = tanhf(s0 + bb.x);
    r.y = tanhf(s1 + bb.y);
    r.z = tanhf(s2 + bb.z);
    r.w = tanhf(s3 + bb.w);
    ((float4*)out)[i] = r;
}

// ---------------------------------------------------------------------------
extern "C" void kernel_launch(void* const* d_in, const int* in_sizes, int n_in,
                              void* d_out, int out_size, void* d_ws, size_t ws_size,
                              hipStream_t stream)
{
    const float* query  = (const float*)d_in[0];
    const float* keys   = (const float*)d_in[1];
    const float* values = (const float*)d_in[2];
    const float* Wq     = (const float*)d_in[3];
    const float* bq     = (const float*)d_in[4];
    const float* watt   = (const float*)d_in[5];
    // d_in[6] = b_att: dropped (softmax shift-invariance)
    const float* Wout   = (const float*)d_in[7];
    const float* bout   = (const float*)d_in[8];

    float* out = (float*)d_out;                    // output 0 (524288 f32)
    float* P   = out + (size_t)B_*TQ*OS;           // output 1 (262144 f32)

    char* base = (char*)d_ws;
    const size_t MB = 1u << 20;
    ushort* Qh  = (ushort*)(base +  0*MB);
    ushort* Ql  = (ushort*)(base +  1*MB);
    ushort* Wqh = (ushort*)(base +  2*MB);
    ushort* Wql = (ushort*)(base +  4*MB);
    ushort* Woh = (ushort*)(base +  6*MB);   // 4 MB (hi only)
    ushort* Vth = (ushort*)(base + 10*MB);   // 4 MB (hi only)
    float*  Ap  = (float*) (base + 14*MB);   // [8][512][1024] = 16 MB
    float*  Ea  = (float*) (base + 30*MB);   // 2 MB
    float*  Sp  = (float*) (base + 32*MB);   // [16][512][512] = 16 MB
    ushort* Ph  = (ushort*)(base + 48*MB);
    ushort* Pl  = (ushort*)(base + 48*MB + 512*1024);
    float*  Ep  = (float*) (base + 49*MB);   // [8][512][1024] = 16 MB
    ushort* Cxh = (ushort*)(base + 65*MB);
    ushort* Cxl = (ushort*)(base + 66*MB);
    float*  Fp  = (float*) (base + 67*MB);   // [8][512][1024] = 16 MB

    // [1] conversions + V transpose (hi only)
    cvt_all_kernel<<<dim3(4096), dim3(256), 0, stream>>>(
        query, Wq, Wout, values, Qh, Ql, Wqh, Wql, Woh, Vth);
    // [2] A-GEMM partials: Q @ Wq^T (3-MFMA, K=1024 split 8 -> 1024 blocks)
    mfma_nt_kernel<<<dim3(16, 8, 8), dim3(256), 0, stream>>>(
        Qh, Ql, Wqh, Wql, Ap, 1024, 1024, 1024, 128, 0);
    // [3] Ea = exp(2*(sum of 8 Ap + bq))
    exp_combine_kernel<<<dim3(512), dim3(256), 0, stream>>>(Ap, bq, Ea);
    // [4] scores v9 (512-thr blocks)
    score_v9_kernel<<<dim3(8, 8, 16), dim3(512), 0, stream>>>(Ea, keys, watt, Sp);
    // [5] softmax -> P (output 1) + Ph/Pl
    softmax_kernel<<<dim3(128), dim3(256), 0, stream>>>(Sp, P, Ph, Pl);
    // [6] PV partials: P @ V (2-MFMA, per-batch, K=512 split 8 -> 1024 blocks)
    mfma_nt2_kernel<<<dim3(16, 8, 8), dim3(256), 0, stream>>>(
        Ph, Pl, Vth, Ep, 512, 512, 1024, 64, VS*TK);
    // [7] Cx = sum of 8 Ep -> hi/lo bf16
    combine_cvt_kernel<<<dim3(512), dim3(256), 0, stream>>>(Ep, Cxh, Cxl);
    // [8] out-GEMM partials (2-MFMA, B hi only; K=2048 split 8 -> 1024 blocks)
    mfma_out_kernel<<<dim3(16, 8, 8), dim3(256), 0, stream>>>(
        Qh, Ql, Cxh, Cxl, Woh, Fp);
    // [9] out = tanh(sum of 8 Fp + bout)
    tanh_combine_kernel<<<dim3(512), dim3(256), 0, stream>>>(Fp, bout, out);
}

// Round 16
// 80.558 us; speedup vs baseline: 1.0692x; 1.0561x over previous
//
#include <hip/hip_runtime.h>
#include <math.h>

static constexpr int B_  = 4;
static constexpr int TQ  = 128;
static constexpr int TK  = 512;
static constexpr int NN  = 1024;
static constexpr int QS  = 1024;
static constexpr int VS  = 1024;
static constexpr int OS  = 1024;

#define K2F    2.8853900817779268f   // 2*log2(e)
#define LOG2EF 1.4426950408889634f
#define SLICE  524288                // 512*1024

typedef __attribute__((ext_vector_type(8))) short bf16x8;
typedef __attribute__((ext_vector_type(4))) float f32x4;

#define MFMA16(a,b,c) __builtin_amdgcn_mfma_f32_16x16x32_bf16((a),(b),(c),0,0,0)

__device__ __forceinline__ ushort bf16_rne(float x) {
    uint u = __float_as_uint(x);
    u += 0x7FFFu + ((u >> 16) & 1u);
    return (ushort)(u >> 16);
}
__device__ __forceinline__ void split2(float x, ushort& h, ushort& l) {
    ushort hh = bf16_rne(x);
    float hv = __uint_as_float((uint)hh << 16);
    h = hh;
    l = bf16_rne(x - hv);
}

// ---------------------------------------------------------------------------
// [1] unified conversion: Q / Wq -> hi/lo, Wout -> hi, V transpose -> hi only
// ---------------------------------------------------------------------------
__global__ __launch_bounds__(256) void cvt_all_kernel(
    const float* __restrict__ Q, const float* __restrict__ Wq,
    const float* __restrict__ Wo, const float* __restrict__ V,
    ushort* __restrict__ Qh, ushort* __restrict__ Ql,
    ushort* __restrict__ Wqh, ushort* __restrict__ Wql,
    ushort* __restrict__ Woh,
    ushort* __restrict__ Vth)
{
    __shared__ float tile[64][65];
    const int bid = blockIdx.x;
    const int t = threadIdx.x;
    if (bid < 3584) {
        if (bid < 1536) {
            const float* src; ushort *h, *l; int idx;
            if (bid < 512) { src = Q;  h = Qh;  l = Ql;  idx = bid*256 + t; }
            else           { src = Wq; h = Wqh; l = Wql; idx = (bid-512)*256 + t; }
            float4 v = ((const float4*)src)[idx];
            ushort4 hh, ll;
            split2(v.x, hh.x, ll.x); split2(v.y, hh.y, ll.y);
            split2(v.z, hh.z, ll.z); split2(v.w, hh.w, ll.w);
            ((ushort4*)h)[idx] = hh;
            ((ushort4*)l)[idx] = ll;
        } else {
            int idx = (bid-1536)*256 + t;
            float4 v = ((const float4*)Wo)[idx];
            ushort4 hh;
            hh.x = bf16_rne(v.x); hh.y = bf16_rne(v.y);
            hh.z = bf16_rne(v.z); hh.w = bf16_rne(v.w);
            ((ushort4*)Woh)[idx] = hh;
        }
        return;
    }
    const int vid = bid - 3584;
    const int v0 = (vid & 15) * 64;
    const int k0 = ((vid >> 4) & 7) * 64;
    const int b  = vid >> 7;
    const float* src = V + ((size_t)b*TK + k0)*VS + v0;
    #pragma unroll
    for (int p = 0; p < 4; ++p) {
        int r = (t >> 4) + p*16, c = (t & 15) * 4;
        float4 vv = *(const float4*)(src + (size_t)r*VS + c);
        tile[r][c] = vv.x; tile[r][c+1] = vv.y; tile[r][c+2] = vv.z; tile[r][c+3] = vv.w;
    }
    __syncthreads();
    ushort* dh = Vth + (size_t)b*(VS*TK) + (size_t)v0*TK + k0;
    #pragma unroll
    for (int p = 0; p < 4; ++p) {
        int vr = (t >> 4) + p*16, kc = (t & 15) * 4;
        ushort4 hh;
        hh.x = bf16_rne(tile[kc+0][vr]);
        hh.y = bf16_rne(tile[kc+1][vr]);
        hh.z = bf16_rne(tile[kc+2][vr]);
        hh.w = bf16_rne(tile[kc+3][vr]);
        *(ushort4*)(dh + (size_t)vr*TK + kc) = hh;
    }
}

// ---------------------------------------------------------------------------
// [2] split-bf16 NT MFMA GEMM (3-MFMA, A+B hi/lo), M=512; A-GEMM. K-split 4.
// ---------------------------------------------------------------------------
__global__ __launch_bounds__(256) void mfma_nt_kernel(
    const ushort* __restrict__ Ah, const ushort* __restrict__ Al,
    const ushort* __restrict__ Bh, const ushort* __restrict__ Bl,
    float* __restrict__ Cp, int lda, int ldb, int Nout, int kchunk, int bstride)
{
    __shared__ alignas(16) ushort lA[2][64][40];
    __shared__ alignas(16) ushort lB[2][64][40];
    const int t = threadIdx.x;
    const int m0 = blockIdx.y * 64, n0 = blockIdx.x * 64, kz = blockIdx.z;
    const int k0 = kz * kchunk;
    const int batch = m0 >> 7;
    const ushort* bhp = Bh + (size_t)batch * bstride;
    const ushort* blp = Bl + (size_t)batch * bstride;
    const int srow = t >> 2, skc = (t & 3) * 8;
    const int lane = t & 63, w = t >> 6;
    const int wm = (w >> 1) * 32, wn = (w & 1) * 32;
    const int fr = lane & 15, fg = (lane >> 4) * 8;

    f32x4 acc00 = {0,0,0,0}, acc01 = {0,0,0,0}, acc10 = {0,0,0,0}, acc11 = {0,0,0,0};

    for (int kb = k0; kb < k0 + kchunk; kb += 32) {
        uint4 va_h = *(const uint4*)(Ah  + (size_t)(m0+srow)*lda + kb + skc);
        uint4 va_l = *(const uint4*)(Al  + (size_t)(m0+srow)*lda + kb + skc);
        uint4 vb_h = *(const uint4*)(bhp + (size_t)(n0+srow)*ldb + kb + skc);
        uint4 vb_l = *(const uint4*)(blp + (size_t)(n0+srow)*ldb + kb + skc);
        *(uint4*)&lA[0][srow][skc] = va_h;
        *(uint4*)&lA[1][srow][skc] = va_l;
        *(uint4*)&lB[0][srow][skc] = vb_h;
        *(uint4*)&lB[1][srow][skc] = vb_l;
        __syncthreads();
        bf16x8 ah0 = *(const bf16x8*)&lA[0][wm + fr     ][fg];
        bf16x8 ah1 = *(const bf16x8*)&lA[0][wm + 16 + fr][fg];
        bf16x8 al0 = *(const bf16x8*)&lA[1][wm + fr     ][fg];
        bf16x8 al1 = *(const bf16x8*)&lA[1][wm + 16 + fr][fg];
        bf16x8 bh0 = *(const bf16x8*)&lB[0][wn + fr     ][fg];
        bf16x8 bh1 = *(const bf16x8*)&lB[0][wn + 16 + fr][fg];
        bf16x8 bl0 = *(const bf16x8*)&lB[1][wn + fr     ][fg];
        bf16x8 bl1 = *(const bf16x8*)&lB[1][wn + 16 + fr][fg];
        acc00 = MFMA16(ah0, bh0, acc00);
        acc00 = MFMA16(al0, bh0, acc00);
        acc00 = MFMA16(ah0, bl0, acc00);
        acc01 = MFMA16(ah0, bh1, acc01);
        acc01 = MFMA16(al0, bh1, acc01);
        acc01 = MFMA16(ah0, bl1, acc01);
        acc10 = MFMA16(ah1, bh0, acc10);
        acc10 = MFMA16(al1, bh0, acc10);
        acc10 = MFMA16(ah1, bl0, acc10);
        acc11 = MFMA16(ah1, bh1, acc11);
        acc11 = MFMA16(al1, bh1, acc11);
        acc11 = MFMA16(ah1, bl1, acc11);
        __syncthreads();
    }
    float* o = Cp + (size_t)kz * 512 * Nout;
    const int orow = (lane >> 4) * 4;
    #pragma unroll
    for (int r2 = 0; r2 < 4; ++r2) {
        o[(size_t)(m0+wm+orow+r2)*Nout      + n0+wn+fr]      = acc00[r2];
        o[(size_t)(m0+wm+orow+r2)*Nout      + n0+wn+16+fr]   = acc01[r2];
        o[(size_t)(m0+wm+16+orow+r2)*Nout   + n0+wn+fr]      = acc10[r2];
        o[(size_t)(m0+wm+16+orow+r2)*Nout   + n0+wn+16+fr]   = acc11[r2];
    }
}

// ---------------------------------------------------------------------------
// [6] 2-MFMA NT GEMM (A hi/lo, B hi only), M=512. PV. K-split 4.
// ---------------------------------------------------------------------------
__global__ __launch_bounds__(256) void mfma_nt2_kernel(
    const ushort* __restrict__ Ah, const ushort* __restrict__ Al,
    const ushort* __restrict__ Bh,
    float* __restrict__ Cp, int lda, int ldb, int Nout, int kchunk, int bstride)
{
    __shared__ alignas(16) ushort lA[2][64][40];
    __shared__ alignas(16) ushort lB[64][40];
    const int t = threadIdx.x;
    const int m0 = blockIdx.y * 64, n0 = blockIdx.x * 64, kz = blockIdx.z;
    const int k0 = kz * kchunk;
    const int batch = m0 >> 7;
    const ushort* bhp = Bh + (size_t)batch * bstride;
    const int srow = t >> 2, skc = (t & 3) * 8;
    const int lane = t & 63, w = t >> 6;
    const int wm = (w >> 1) * 32, wn = (w & 1) * 32;
    const int fr = lane & 15, fg = (lane >> 4) * 8;

    f32x4 acc00 = {0,0,0,0}, acc01 = {0,0,0,0}, acc10 = {0,0,0,0}, acc11 = {0,0,0,0};

    for (int kb = k0; kb < k0 + kchunk; kb += 32) {
        *(uint4*)&lA[0][srow][skc] = *(const uint4*)(Ah  + (size_t)(m0+srow)*lda + kb + skc);
        *(uint4*)&lA[1][srow][skc] = *(const uint4*)(Al  + (size_t)(m0+srow)*lda + kb + skc);
        *(uint4*)&lB[srow][skc]    = *(const uint4*)(bhp + (size_t)(n0+srow)*ldb + kb + skc);
        __syncthreads();
        bf16x8 ah0 = *(const bf16x8*)&lA[0][wm + fr     ][fg];
        bf16x8 ah1 = *(const bf16x8*)&lA[0][wm + 16 + fr][fg];
        bf16x8 al0 = *(const bf16x8*)&lA[1][wm + fr     ][fg];
        bf16x8 al1 = *(const bf16x8*)&lA[1][wm + 16 + fr][fg];
        bf16x8 bh0 = *(const bf16x8*)&lB[wn + fr     ][fg];
        bf16x8 bh1 = *(const bf16x8*)&lB[wn + 16 + fr][fg];
        acc00 = MFMA16(ah0, bh0, acc00);
        acc00 = MFMA16(al0, bh0, acc00);
        acc01 = MFMA16(ah0, bh1, acc01);
        acc01 = MFMA16(al0, bh1, acc01);
        acc10 = MFMA16(ah1, bh0, acc10);
        acc10 = MFMA16(al1, bh0, acc10);
        acc11 = MFMA16(ah1, bh1, acc11);
        acc11 = MFMA16(al1, bh1, acc11);
        __syncthreads();
    }
    float* o = Cp + (size_t)kz * 512 * Nout;
    const int orow = (lane >> 4) * 4;
    #pragma unroll
    for (int r2 = 0; r2 < 4; ++r2) {
        o[(size_t)(m0+wm+orow+r2)*Nout      + n0+wn+fr]      = acc00[r2];
        o[(size_t)(m0+wm+orow+r2)*Nout      + n0+wn+16+fr]   = acc01[r2];
        o[(size_t)(m0+wm+16+orow+r2)*Nout   + n0+wn+fr]      = acc10[r2];
        o[(size_t)(m0+wm+16+orow+r2)*Nout   + n0+wn+16+fr]   = acc11[r2];
    }
}

// ---------------------------------------------------------------------------
// [3] Ea = exp2((sum of 4 Ap slices + bq) * K2F)
// ---------------------------------------------------------------------------
__global__ __launch_bounds__(256) void exp_combine_kernel(
    const float* __restrict__ Ap, const float* __restrict__ bias,
    float* __restrict__ E)
{
    int i = blockIdx.x * 256 + threadIdx.x;
    float4 p0 = ((const float4*)Ap)[i];
    float4 p1 = ((const float4*)(Ap + SLICE))[i];
    float4 p2 = ((const float4*)(Ap + 2*SLICE))[i];
    float4 p3 = ((const float4*)(Ap + 3*SLICE))[i];
    float4 bb = ((const float4*)bias)[i & 255];
    float4 r;
    r.x = exp2f((p0.x+p1.x+p2.x+p3.x+bb.x) * K2F);
    r.y = exp2f((p0.y+p1.y+p2.y+p3.y+bb.y) * K2F);
    r.z = exp2f((p0.z+p1.z+p2.z+p3.z+bb.z) * K2F);
    r.w = exp2f((p0.w+p1.w+p2.w+p3.w+bb.w) * K2F);
    ((float4*)E)[i] = r;
}

// ---------------------------------------------------------------------------
// [4] scores v11: 512-thread blocks, 64q x 64k x 64n tile, 2x4/thread,
// QUAD-rcp: w0/A+w1/B+w2/C+w3/D = (n01*CD + n23*AB)*rcp(A*B*C*D)
// -> 14 VALU + 1 rcp per 4 evals. Grid 8x8x16 = 1024 blocks.
// ---------------------------------------------------------------------------
__global__ __launch_bounds__(512, 4) void score_v11_kernel(
    const float* __restrict__ Ea,   // [512][1024]
    const float* __restrict__ keys,
    const float* __restrict__ watt,
    float* __restrict__ Sp)         // [16][512][512]
{
    __shared__ float ea[64][66];
    __shared__ float ek[64][68];
    __shared__ float wl[64];
    const int tid = threadIdx.x;
    const int kt = blockIdx.x;      // 0..7
    const int qt = blockIdx.y;      // 0..7
    const int nh = blockIdx.z;      // 0..15
    const int nbeg = nh * 64;
    const int q0 = qt * 64;
    const int b  = qt >> 1;
    const int k0 = b*TK + kt*64;

    {   // stage ea[n][q]
        const int q = tid >> 3;
        const int nc = (tid & 7) * 8;
        const float* ep = Ea + (size_t)(q0 + q)*NN + nbeg + nc;
        float4 e0 = *(const float4*)(ep);
        float4 e1 = *(const float4*)(ep + 4);
        ea[nc+0][q] = e0.x; ea[nc+1][q] = e0.y; ea[nc+2][q] = e0.z; ea[nc+3][q] = e0.w;
        ea[nc+4][q] = e1.x; ea[nc+5][q] = e1.y; ea[nc+6][q] = e1.z; ea[nc+7][q] = e1.w;
    }
    {   // stage ek[n][k] with exp2
        const int k = tid >> 3;
        const int nc = (tid & 7) * 8;
        const float* kp = keys + (size_t)(k0 + k)*NN + nbeg + nc;
        float4 k0v = *(const float4*)(kp);
        float4 k1v = *(const float4*)(kp + 4);
        ek[nc+0][k] = exp2f(k0v.x * K2F);
        ek[nc+1][k] = exp2f(k0v.y * K2F);
        ek[nc+2][k] = exp2f(k0v.z * K2F);
        ek[nc+3][k] = exp2f(k0v.w * K2F);
        ek[nc+4][k] = exp2f(k1v.x * K2F);
        ek[nc+5][k] = exp2f(k1v.y * K2F);
        ek[nc+6][k] = exp2f(k1v.z * K2F);
        ek[nc+7][k] = exp2f(k1v.w * K2F);
    }
    if (tid < 64) wl[tid] = watt[nbeg + tid];
    __syncthreads();

    const int tx = tid & 15;
    const int ty = tid >> 4;
    float acc[2][4] = {};
    #pragma unroll 4
    for (int g = 0; g < 16; ++g) {
        float2 e0 = *(const float2*)&ea[4*g+0][ty*2];
        float2 e1 = *(const float2*)&ea[4*g+1][ty*2];
        float2 e2 = *(const float2*)&ea[4*g+2][ty*2];
        float2 e3 = *(const float2*)&ea[4*g+3][ty*2];
        float4 f0 = *(const float4*)&ek[4*g+0][tx*4];
        float4 f1 = *(const float4*)&ek[4*g+1][tx*4];
        float4 f2 = *(const float4*)&ek[4*g+2][tx*4];
        float4 f3 = *(const float4*)&ek[4*g+3][tx*4];
        float4 w4 = *(const float4*)&wl[4*g];
        float E0[2] = {e0.x, e0.y};
        float E1[2] = {e1.x, e1.y};
        float E2[2] = {e2.x, e2.y};
        float E3[2] = {e3.x, e3.y};
        float F0[4] = {f0.x, f0.y, f0.z, f0.w};
        float F1[4] = {f1.x, f1.y, f1.z, f1.w};
        float F2[4] = {f2.x, f2.y, f2.z, f2.w};
        float F3[4] = {f3.x, f3.y, f3.z, f3.w};
        #pragma unroll
        for (int i = 0; i < 2; ++i) {
            #pragma unroll
            for (int j = 0; j < 4; ++j) {
                float A  = fmaf(E0[i], F0[j], 1.0f);
                float Bv = fmaf(E1[i], F1[j], 1.0f);
                float C  = fmaf(E2[i], F2[j], 1.0f);
                float D  = fmaf(E3[i], F3[j], 1.0f);
                float AB = A * Bv;
                float CD = C * D;
                float n01 = fmaf(w4.x, Bv, w4.y * A);
                float n23 = fmaf(w4.z, D,  w4.w * C);
                float num = fmaf(n01, CD, n23 * AB);
                acc[i][j] = fmaf(num, __builtin_amdgcn_rcpf(AB * CD), acc[i][j]);
            }
        }
    }
    float* o = Sp + ((size_t)nh*512 + q0 + ty*2)*TK + kt*64 + tx*4;
    #pragma unroll
    for (int i = 0; i < 2; ++i) {
        float4 r = {-2.0f*acc[i][0], -2.0f*acc[i][1], -2.0f*acc[i][2], -2.0f*acc[i][3]};
        *(float4*)(o + (size_t)i*TK) = r;
    }
}

// ---------------------------------------------------------------------------
// [5] softmax over k of sum_{h<16} Sp[h]; P f32 + Ph/Pl
// ---------------------------------------------------------------------------
__global__ __launch_bounds__(256) void softmax_kernel(
    const float* __restrict__ Sp, float* __restrict__ P,
    ushort* __restrict__ Ph, ushort* __restrict__ Pl)
{
    const int lane = threadIdx.x & 63;
    const int wid  = threadIdx.x >> 6;
    const int row  = blockIdx.x * 4 + wid;
    const size_t S = (size_t)512*512;
    float v[8];
    float m = -3.4e38f;
    #pragma unroll
    for (int j = 0; j < 8; ++j) {
        int k = lane + j*64;
        float s = 0.f;
        #pragma unroll
        for (int h = 0; h < 16; ++h)
            s += Sp[h*S + (size_t)row*TK + k];
        v[j] = s;
        m = fmaxf(m, v[j]);
    }
    #pragma unroll
    for (int off = 32; off; off >>= 1) m = fmaxf(m, __shfl_xor(m, off, 64));
    float sum = 0.f;
    #pragma unroll
    for (int j = 0; j < 8; ++j) { v[j] = exp2f((v[j] - m) * LOG2EF); sum += v[j]; }
    #pragma unroll
    for (int off = 32; off; off >>= 1) sum += __shfl_xor(sum, off, 64);
    float inv = 1.0f / sum;
    #pragma unroll
    for (int j = 0; j < 8; ++j) {
        int k = lane + j*64;
        float pv = v[j] * inv;
        P[(size_t)row * TK + k] = pv;
        ushort h, l; split2(pv, h, l);
        Ph[(size_t)row * TK + k] = h;
        Pl[(size_t)row * TK + k] = l;
    }
}

// ---------------------------------------------------------------------------
// [7] Cx = sum of 4 Ep slices -> hi/lo bf16
// ---------------------------------------------------------------------------
__global__ __launch_bounds__(256) void combine_cvt_kernel(
    const float* __restrict__ Ep, ushort* __restrict__ Ch, ushort* __restrict__ Cl)
{
    int i = blockIdx.x * 256 + threadIdx.x;
    float4 p0 = ((const float4*)Ep)[i];
    float4 p1 = ((const float4*)(Ep + SLICE))[i];
    float4 p2 = ((const float4*)(Ep + 2*SLICE))[i];
    float4 p3 = ((const float4*)(Ep + 3*SLICE))[i];
    float4 s = {p0.x+p1.x+p2.x+p3.x, p0.y+p1.y+p2.y+p3.y,
                p0.z+p1.z+p2.z+p3.z, p0.w+p1.w+p2.w+p3.w};
    ushort4 hh, ll;
    split2(s.x, hh.x, ll.x); split2(s.y, hh.y, ll.y);
    split2(s.z, hh.z, ll.z); split2(s.w, hh.w, ll.w);
    ((ushort4*)Ch)[i] = hh;
    ((ushort4*)Cl)[i] = ll;
}

// ---------------------------------------------------------------------------
// [8] out-GEMM: A = [Q hi/lo | Cx hi/lo], B = Woh only (2-MFMA). K=2048/4.
// ---------------------------------------------------------------------------
__global__ __launch_bounds__(256) void mfma_out_kernel(
    const ushort* __restrict__ Qh, const ushort* __restrict__ Ql,
    const ushort* __restrict__ Cxh, const ushort* __restrict__ Cxl,
    const ushort* __restrict__ Wh,  // [1024][2048] hi
    float* __restrict__ Fp)
{
    __shared__ alignas(16) ushort lA[2][64][40];
    __shared__ alignas(16) ushort lB[64][40];
    const int t = threadIdx.x;
    const int m0 = blockIdx.y * 64, n0 = blockIdx.x * 64, kz = blockIdx.z;
    const ushort* ah_p = (kz < 2) ? Qh : Cxh;
    const ushort* al_p = (kz < 2) ? Ql : Cxl;
    const int akoff = (kz & 1) * 512;
    const int bkoff = kz * 512;
    const int srow = t >> 2, skc = (t & 3) * 8;
    const int lane = t & 63, w = t >> 6;
    const int wm = (w >> 1) * 32, wn = (w & 1) * 32;
    const int fr = lane & 15, fg = (lane >> 4) * 8;

    f32x4 acc00 = {0,0,0,0}, acc01 = {0,0,0,0}, acc10 = {0,0,0,0}, acc11 = {0,0,0,0};

    for (int kk = 0; kk < 512; kk += 32) {
        size_t aoff = (size_t)(m0+srow)*1024 + akoff + kk + skc;
        *(uint4*)&lA[0][srow][skc] = *(const uint4*)(ah_p + aoff);
        *(uint4*)&lA[1][srow][skc] = *(const uint4*)(al_p + aoff);
        *(uint4*)&lB[srow][skc] =
            *(const uint4*)(Wh + (size_t)(n0+srow)*2048 + bkoff + kk + skc);
        __syncthreads();
        bf16x8 ah0 = *(const bf16x8*)&lA[0][wm + fr     ][fg];
        bf16x8 ah1 = *(const bf16x8*)&lA[0][wm + 16 + fr][fg];
        bf16x8 al0 = *(const bf16x8*)&lA[1][wm + fr     ][fg];
        bf16x8 al1 = *(const bf16x8*)&lA[1][wm + 16 + fr][fg];
        bf16x8 bh0 = *(const bf16x8*)&lB[wn + fr     ][fg];
        bf16x8 bh1 = *(const bf16x8*)&lB[wn + 16 + fr][fg];
        acc00 = MFMA16(ah0, bh0, acc00);
        acc00 = MFMA16(al0, bh0, acc00);
        acc01 = MFMA16(ah0, bh1, acc01);
        acc01 = MFMA16(al0, bh1, acc01);
        acc10 = MFMA16(ah1, bh0, acc10);
        acc10 = MFMA16(al1, bh0, acc10);
        acc11 = MFMA16(ah1, bh1, acc11);
        acc11 = MFMA16(al1, bh1, acc11);
        __syncthreads();
    }
    float* o = Fp + (size_t)kz * SLICE;
    const int orow = (lane >> 4) * 4;
    #pragma unroll
    for (int r2 = 0; r2 < 4; ++r2) {
        o[(size_t)(m0+wm+orow+r2)*1024    + n0+wn+fr]    = acc00[r2];
        o[(size_t)(m0+wm+orow+r2)*1024    + n0+wn+16+fr] = acc01[r2];
        o[(size_t)(m0+wm+16+orow+r2)*1024 + n0+wn+fr]    = acc10[r2];
        o[(size_t)(m0+wm+16+orow+r2)*1024 + n0+wn+16+fr] = acc11[r2];
    }
}

// ---------------------------------------------------------------------------
// [9] out = tanh(sum Fp + bias)
// ---------------------------------------------------------------------------
__global__ __launch_bounds__(256) void tanh_combine_kernel(
    const float* __restrict__ Fp, const float* __restrict__ bias,
    float* __restrict__ out)
{
    int i = blockIdx.x * 256 + threadIdx.x;
    const size_t S = (size_t)B_*TQ*OS;
    float4 p0 = ((const float4*)Fp)[i];
    float4 p1 = ((const float4*)(Fp + S))[i];
    float4 p2 = ((const float4*)(Fp + 2*S))[i];
    float4 p3 = ((const float4*)(Fp + 3*S))[i];
    float4 bb = ((const float4*)bias)[i & 255];
    float4 r;
    r.x = tanhf(p0.x + p1.x + p2.x + p3.x + bb.x);
    r.y = tanhf(p0.y + p1.y + p2.y + p3.y + bb.y);
    r.z = tanhf(p0.z + p1.z + p2.z + p3.z + bb.z);
    r.w = tanhf(p0.w + p1.w + p2.w + p3.w + bb.w);
    ((float4*)out)[i] = r;
}

// ---------------------------------------------------------------------------
extern "C" void kernel_launch(void* const* d_in, const int* in_sizes, int n_in,
                              void* d_out, int out_size, void* d_ws, size_t ws_size,
                              hipStream_t stream)
{
    const float* query  = (const float*)d_in[0];
    const float* keys   = (const float*)d_in[1];
    const float* values = (const float*)d_in[2];
    const float* Wq     = (const float*)d_in[3];
    const float* bq     = (const float*)d_in[4];
    const float* watt   = (const float*)d_in[5];
    // d_in[6] = b_att: dropped (softmax shift-invariance)
    const float* Wout   = (const float*)d_in[7];
    const float* bout   = (const float*)d_in[8];

    float* out = (float*)d_out;                    // output 0 (524288 f32)
    float* P   = out + (size_t)B_*TQ*OS;           // output 1 (262144 f32)

    char* base = (char*)d_ws;
    const size_t MB = 1u << 20;
    ushort* Qh  = (ushort*)(base +  0*MB);
    ushort* Ql  = (ushort*)(base +  1*MB);
    ushort* Wqh = (ushort*)(base +  2*MB);
    ushort* Wql = (ushort*)(base +  4*MB);
    ushort* Woh = (ushort*)(base +  6*MB);   // 4 MB (hi only)
    ushort* Vth = (ushort*)(base + 10*MB);   // 4 MB (hi only)
    float*  Ap  = (float*) (base + 14*MB);   // [4][512][1024] = 8 MB
    float*  Ea  = (float*) (base + 22*MB);   // 2 MB
    float*  Sp  = (float*) (base + 24*MB);   // [16][512][512] = 16 MB
    ushort* Ph  = (ushort*)(base + 40*MB);
    ushort* Pl  = (ushort*)(base + 40*MB + 512*1024);
    float*  Ep  = (float*) (base + 41*MB);   // [4][512][1024] = 8 MB
    ushort* Cxh = (ushort*)(base + 49*MB);
    ushort* Cxl = (ushort*)(base + 50*MB);
    float*  Fp  = (float*) (base + 51*MB);   // [4][512][1024] = 8 MB

    // [1] conversions + V transpose (hi only)
    cvt_all_kernel<<<dim3(4096), dim3(256), 0, stream>>>(
        query, Wq, Wout, values, Qh, Ql, Wqh, Wql, Woh, Vth);
    // [2] A-GEMM partials: Q @ Wq^T (3-MFMA, K=1024 split 4)
    mfma_nt_kernel<<<dim3(16, 8, 4), dim3(256), 0, stream>>>(
        Qh, Ql, Wqh, Wql, Ap, 1024, 1024, 1024, 256, 0);
    // [3] Ea = exp(2*(sum Ap + bq))
    exp_combine_kernel<<<dim3(512), dim3(256), 0, stream>>>(Ap, bq, Ea);
    // [4] scores v11 (quad-rcp)
    score_v11_kernel<<<dim3(8, 8, 16), dim3(512), 0, stream>>>(Ea, keys, watt, Sp);
    // [5] softmax -> P (output 1) + Ph/Pl
    softmax_kernel<<<dim3(128), dim3(256), 0, stream>>>(Sp, P, Ph, Pl);
    // [6] PV partials: P @ V (2-MFMA, per-batch, K=512 split 4)
    mfma_nt2_kernel<<<dim3(16, 8, 4), dim3(256), 0, stream>>>(
        Ph, Pl, Vth, Ep, 512, 512, 1024, 128, VS*TK);
    // [7] Cx = sum Ep -> hi/lo bf16
    combine_cvt_kernel<<<dim3(512), dim3(256), 0, stream>>>(Ep, Cxh, Cxl);
    // [8] out-GEMM partials (2-MFMA, B hi only; K=2048 split 4)
    mfma_out_kernel<<<dim3(16, 8, 4), dim3(256), 0, stream>>>(
        Qh, Ql, Cxh, Cxl, Woh, Fp);
    // [9] out = tanh(sum + bout)
    tanh_combine_kernel<<<dim3(512), dim3(256), 0, stream>>>(Fp, bout, out);
}

// Round 17
// 79.575 us; speedup vs baseline: 1.0824x; 1.0124x over previous
//
#include <hip/hip_runtime.h>
#include <math.h>

static constexpr int B_  = 4;
static constexpr int TQ  = 128;
static constexpr int TK  = 512;
static constexpr int NN  = 1024;
static constexpr int QS  = 1024;
static constexpr int VS  = 1024;
static constexpr int OS  = 1024;

#define K2F    2.8853900817779268f   // 2*log2(e)
#define LOG2EF 1.4426950408889634f
#define SLICE  524288                // 512*1024

typedef __attribute__((ext_vector_type(8))) short bf16x8;
typedef __attribute__((ext_vector_type(4))) float f32x4;

#define MFMA16(a,b,c) __builtin_amdgcn_mfma_f32_16x16x32_bf16((a),(b),(c),0,0,0)

__device__ __forceinline__ ushort bf16_rne(float x) {
    uint u = __float_as_uint(x);
    u += 0x7FFFu + ((u >> 16) & 1u);
    return (ushort)(u >> 16);
}
__device__ __forceinline__ void split2(float x, ushort& h, ushort& l) {
    ushort hh = bf16_rne(x);
    float hv = __uint_as_float((uint)hh << 16);
    h = hh;
    l = bf16_rne(x - hv);
}

// ---------------------------------------------------------------------------
// [1] unified conversion: Q / Wq -> hi/lo, Wout -> hi, V transpose -> hi only
// ---------------------------------------------------------------------------
__global__ __launch_bounds__(256) void cvt_all_kernel(
    const float* __restrict__ Q, const float* __restrict__ Wq,
    const float* __restrict__ Wo, const float* __restrict__ V,
    ushort* __restrict__ Qh, ushort* __restrict__ Ql,
    ushort* __restrict__ Wqh, ushort* __restrict__ Wql,
    ushort* __restrict__ Woh,
    ushort* __restrict__ Vth)
{
    __shared__ float tile[64][65];
    const int bid = blockIdx.x;
    const int t = threadIdx.x;
    if (bid < 3584) {
        if (bid < 1536) {
            const float* src; ushort *h, *l; int idx;
            if (bid < 512) { src = Q;  h = Qh;  l = Ql;  idx = bid*256 + t; }
            else           { src = Wq; h = Wqh; l = Wql; idx = (bid-512)*256 + t; }
            float4 v = ((const float4*)src)[idx];
            ushort4 hh, ll;
            split2(v.x, hh.x, ll.x); split2(v.y, hh.y, ll.y);
            split2(v.z, hh.z, ll.z); split2(v.w, hh.w, ll.w);
            ((ushort4*)h)[idx] = hh;
            ((ushort4*)l)[idx] = ll;
        } else {
            int idx = (bid-1536)*256 + t;
            float4 v = ((const float4*)Wo)[idx];
            ushort4 hh;
            hh.x = bf16_rne(v.x); hh.y = bf16_rne(v.y);
            hh.z = bf16_rne(v.z); hh.w = bf16_rne(v.w);
            ((ushort4*)Woh)[idx] = hh;
        }
        return;
    }
    const int vid = bid - 3584;
    const int v0 = (vid & 15) * 64;
    const int k0 = ((vid >> 4) & 7) * 64;
    const int b  = vid >> 7;
    const float* src = V + ((size_t)b*TK + k0)*VS + v0;
    #pragma unroll
    for (int p = 0; p < 4; ++p) {
        int r = (t >> 4) + p*16, c = (t & 15) * 4;
        float4 vv = *(const float4*)(src + (size_t)r*VS + c);
        tile[r][c] = vv.x; tile[r][c+1] = vv.y; tile[r][c+2] = vv.z; tile[r][c+3] = vv.w;
    }
    __syncthreads();
    ushort* dh = Vth + (size_t)b*(VS*TK) + (size_t)v0*TK + k0;
    #pragma unroll
    for (int p = 0; p < 4; ++p) {
        int vr = (t >> 4) + p*16, kc = (t & 15) * 4;
        ushort4 hh;
        hh.x = bf16_rne(tile[kc+0][vr]);
        hh.y = bf16_rne(tile[kc+1][vr]);
        hh.z = bf16_rne(tile[kc+2][vr]);
        hh.w = bf16_rne(tile[kc+3][vr]);
        *(ushort4*)(dh + (size_t)vr*TK + kc) = hh;
    }
}

// ---------------------------------------------------------------------------
// [2] split-bf16 NT MFMA GEMM (3-MFMA, A+B hi/lo), M=512; A-GEMM. K-split 4.
// ---------------------------------------------------------------------------
__global__ __launch_bounds__(256) void mfma_nt_kernel(
    const ushort* __restrict__ Ah, const ushort* __restrict__ Al,
    const ushort* __restrict__ Bh, const ushort* __restrict__ Bl,
    float* __restrict__ Cp, int lda, int ldb, int Nout, int kchunk, int bstride)
{
    __shared__ alignas(16) ushort lA[2][64][40];
    __shared__ alignas(16) ushort lB[2][64][40];
    const int t = threadIdx.x;
    const int m0 = blockIdx.y * 64, n0 = blockIdx.x * 64, kz = blockIdx.z;
    const int k0 = kz * kchunk;
    const int batch = m0 >> 7;
    const ushort* bhp = Bh + (size_t)batch * bstride;
    const ushort* blp = Bl + (size_t)batch * bstride;
    const int srow = t >> 2, skc = (t & 3) * 8;
    const int lane = t & 63, w = t >> 6;
    const int wm = (w >> 1) * 32, wn = (w & 1) * 32;
    const int fr = lane & 15, fg = (lane >> 4) * 8;

    f32x4 acc00 = {0,0,0,0}, acc01 = {0,0,0,0}, acc10 = {0,0,0,0}, acc11 = {0,0,0,0};

    for (int kb = k0; kb < k0 + kchunk; kb += 32) {
        uint4 va_h = *(const uint4*)(Ah  + (size_t)(m0+srow)*lda + kb + skc);
        uint4 va_l = *(const uint4*)(Al  + (size_t)(m0+srow)*lda + kb + skc);
        uint4 vb_h = *(const uint4*)(bhp + (size_t)(n0+srow)*ldb + kb + skc);
        uint4 vb_l = *(const uint4*)(blp + (size_t)(n0+srow)*ldb + kb + skc);
        *(uint4*)&lA[0][srow][skc] = va_h;
        *(uint4*)&lA[1][srow][skc] = va_l;
        *(uint4*)&lB[0][srow][skc] = vb_h;
        *(uint4*)&lB[1][srow][skc] = vb_l;
        __syncthreads();
        bf16x8 ah0 = *(const bf16x8*)&lA[0][wm + fr     ][fg];
        bf16x8 ah1 = *(const bf16x8*)&lA[0][wm + 16 + fr][fg];
        bf16x8 al0 = *(const bf16x8*)&lA[1][wm + fr     ][fg];
        bf16x8 al1 = *(const bf16x8*)&lA[1][wm + 16 + fr][fg];
        bf16x8 bh0 = *(const bf16x8*)&lB[0][wn + fr     ][fg];
        bf16x8 bh1 = *(const bf16x8*)&lB[0][wn + 16 + fr][fg];
        bf16x8 bl0 = *(const bf16x8*)&lB[1][wn + fr     ][fg];
        bf16x8 bl1 = *(const bf16x8*)&lB[1][wn + 16 + fr][fg];
        acc00 = MFMA16(ah0, bh0, acc00);
        acc00 = MFMA16(al0, bh0, acc00);
        acc00 = MFMA16(ah0, bl0, acc00);
        acc01 = MFMA16(ah0, bh1, acc01);
        acc01 = MFMA16(al0, bh1, acc01);
        acc01 = MFMA16(ah0, bl1, acc01);
        acc10 = MFMA16(ah1, bh0, acc10);
        acc10 = MFMA16(al1, bh0, acc10);
        acc10 = MFMA16(ah1, bl0, acc10);
        acc11 = MFMA16(ah1, bh1, acc11);
        acc11 = MFMA16(al1, bh1, acc11);
        acc11 = MFMA16(ah1, bl1, acc11);
        __syncthreads();
    }
    float* o = Cp + (size_t)kz * 512 * Nout;
    const int orow = (lane >> 4) * 4;
    #pragma unroll
    for (int r2 = 0; r2 < 4; ++r2) {
        o[(size_t)(m0+wm+orow+r2)*Nout      + n0+wn+fr]      = acc00[r2];
        o[(size_t)(m0+wm+orow+r2)*Nout      + n0+wn+16+fr]   = acc01[r2];
        o[(size_t)(m0+wm+16+orow+r2)*Nout   + n0+wn+fr]      = acc10[r2];
        o[(size_t)(m0+wm+16+orow+r2)*Nout   + n0+wn+16+fr]   = acc11[r2];
    }
}

// ---------------------------------------------------------------------------
// [6] 2-MFMA NT GEMM (A hi/lo, B hi only), M=512. PV. K-split 4.
// ---------------------------------------------------------------------------
__global__ __launch_bounds__(256) void mfma_nt2_kernel(
    const ushort* __restrict__ Ah, const ushort* __restrict__ Al,
    const ushort* __restrict__ Bh,
    float* __restrict__ Cp, int lda, int ldb, int Nout, int kchunk, int bstride)
{
    __shared__ alignas(16) ushort lA[2][64][40];
    __shared__ alignas(16) ushort lB[64][40];
    const int t = threadIdx.x;
    const int m0 = blockIdx.y * 64, n0 = blockIdx.x * 64, kz = blockIdx.z;
    const int k0 = kz * kchunk;
    const int batch = m0 >> 7;
    const ushort* bhp = Bh + (size_t)batch * bstride;
    const int srow = t >> 2, skc = (t & 3) * 8;
    const int lane = t & 63, w = t >> 6;
    const int wm = (w >> 1) * 32, wn = (w & 1) * 32;
    const int fr = lane & 15, fg = (lane >> 4) * 8;

    f32x4 acc00 = {0,0,0,0}, acc01 = {0,0,0,0}, acc10 = {0,0,0,0}, acc11 = {0,0,0,0};

    for (int kb = k0; kb < k0 + kchunk; kb += 32) {
        *(uint4*)&lA[0][srow][skc] = *(const uint4*)(Ah  + (size_t)(m0+srow)*lda + kb + skc);
        *(uint4*)&lA[1][srow][skc] = *(const uint4*)(Al  + (size_t)(m0+srow)*lda + kb + skc);
        *(uint4*)&lB[srow][skc]    = *(const uint4*)(bhp + (size_t)(n0+srow)*ldb + kb + skc);
        __syncthreads();
        bf16x8 ah0 = *(const bf16x8*)&lA[0][wm + fr     ][fg];
        bf16x8 ah1 = *(const bf16x8*)&lA[0][wm + 16 + fr][fg];
        bf16x8 al0 = *(const bf16x8*)&lA[1][wm + fr     ][fg];
        bf16x8 al1 = *(const bf16x8*)&lA[1][wm + 16 + fr][fg];
        bf16x8 bh0 = *(const bf16x8*)&lB[wn + fr     ][fg];
        bf16x8 bh1 = *(const bf16x8*)&lB[wn + 16 + fr][fg];
        acc00 = MFMA16(ah0, bh0, acc00);
        acc00 = MFMA16(al0, bh0, acc00);
        acc01 = MFMA16(ah0, bh1, acc01);
        acc01 = MFMA16(al0, bh1, acc01);
        acc10 = MFMA16(ah1, bh0, acc10);
        acc10 = MFMA16(al1, bh0, acc10);
        acc11 = MFMA16(ah1, bh1, acc11);
        acc11 = MFMA16(al1, bh1, acc11);
        __syncthreads();
    }
    float* o = Cp + (size_t)kz * 512 * Nout;
    const int orow = (lane >> 4) * 4;
    #pragma unroll
    for (int r2 = 0; r2 < 4; ++r2) {
        o[(size_t)(m0+wm+orow+r2)*Nout      + n0+wn+fr]      = acc00[r2];
        o[(size_t)(m0+wm+orow+r2)*Nout      + n0+wn+16+fr]   = acc01[r2];
        o[(size_t)(m0+wm+16+orow+r2)*Nout   + n0+wn+fr]      = acc10[r2];
        o[(size_t)(m0+wm+16+orow+r2)*Nout   + n0+wn+16+fr]   = acc11[r2];
    }
}

// ---------------------------------------------------------------------------
// [3] Ea = exp2((sum of 4 Ap slices + bq) * K2F)
// ---------------------------------------------------------------------------
__global__ __launch_bounds__(256) void exp_combine_kernel(
    const float* __restrict__ Ap, const float* __restrict__ bias,
    float* __restrict__ E)
{
    int i = blockIdx.x * 256 + threadIdx.x;
    float4 p0 = ((const float4*)Ap)[i];
    float4 p1 = ((const float4*)(Ap + SLICE))[i];
    float4 p2 = ((const float4*)(Ap + 2*SLICE))[i];
    float4 p3 = ((const float4*)(Ap + 3*SLICE))[i];
    float4 bb = ((const float4*)bias)[i & 255];
    float4 r;
    r.x = exp2f((p0.x+p1.x+p2.x+p3.x+bb.x) * K2F);
    r.y = exp2f((p0.y+p1.y+p2.y+p3.y+bb.y) * K2F);
    r.z = exp2f((p0.z+p1.z+p2.z+p3.z+bb.z) * K2F);
    r.w = exp2f((p0.w+p1.w+p2.w+p3.w+bb.w) * K2F);
    ((float4*)E)[i] = r;
}

// ---------------------------------------------------------------------------
// [4] scores v12: 512-thread blocks, 64q x 64k x 128n per block (two 64-n
// staged halves, acc carried), 2x4/thread, QUAD-rcp. Grid 8x8x8 = 512 blocks.
// Sp has 8 slices (8 MB).
// ---------------------------------------------------------------------------
__global__ __launch_bounds__(512, 4) void score_v12_kernel(
    const float* __restrict__ Ea,   // [512][1024]
    const float* __restrict__ keys,
    const float* __restrict__ watt,
    float* __restrict__ Sp)         // [8][512][512]
{
    __shared__ float ea[64][66];
    __shared__ float ek[64][68];
    __shared__ float wl[64];
    const int tid = threadIdx.x;
    const int kt = blockIdx.x;      // 0..7
    const int qt = blockIdx.y;      // 0..7
    const int nh = blockIdx.z;      // 0..7
    const int q0 = qt * 64;
    const int b  = qt >> 1;
    const int k0 = b*TK + kt*64;
    const int tx = tid & 15;
    const int ty = tid >> 4;
    float acc[2][4] = {};

    #pragma unroll
    for (int half = 0; half < 2; ++half) {
        const int nbeg = nh*128 + half*64;
        if (half) __syncthreads();          // protect LDS before restage
        {   // stage ea[n][q]
            const int q = tid >> 3;
            const int nc = (tid & 7) * 8;
            const float* ep = Ea + (size_t)(q0 + q)*NN + nbeg + nc;
            float4 e0 = *(const float4*)(ep);
            float4 e1 = *(const float4*)(ep + 4);
            ea[nc+0][q] = e0.x; ea[nc+1][q] = e0.y; ea[nc+2][q] = e0.z; ea[nc+3][q] = e0.w;
            ea[nc+4][q] = e1.x; ea[nc+5][q] = e1.y; ea[nc+6][q] = e1.z; ea[nc+7][q] = e1.w;
        }
        {   // stage ek[n][k] with exp2
            const int k = tid >> 3;
            const int nc = (tid & 7) * 8;
            const float* kp = keys + (size_t)(k0 + k)*NN + nbeg + nc;
            float4 k0v = *(const float4*)(kp);
            float4 k1v = *(const float4*)(kp + 4);
            ek[nc+0][k] = exp2f(k0v.x * K2F);
            ek[nc+1][k] = exp2f(k0v.y * K2F);
            ek[nc+2][k] = exp2f(k0v.z * K2F);
            ek[nc+3][k] = exp2f(k0v.w * K2F);
            ek[nc+4][k] = exp2f(k1v.x * K2F);
            ek[nc+5][k] = exp2f(k1v.y * K2F);
            ek[nc+6][k] = exp2f(k1v.z * K2F);
            ek[nc+7][k] = exp2f(k1v.w * K2F);
        }
        if (tid < 64) wl[tid] = watt[nbeg + tid];
        __syncthreads();

        #pragma unroll 4
        for (int g = 0; g < 16; ++g) {
            float2 e0 = *(const float2*)&ea[4*g+0][ty*2];
            float2 e1 = *(const float2*)&ea[4*g+1][ty*2];
            float2 e2 = *(const float2*)&ea[4*g+2][ty*2];
            float2 e3 = *(const float2*)&ea[4*g+3][ty*2];
            float4 f0 = *(const float4*)&ek[4*g+0][tx*4];
            float4 f1 = *(const float4*)&ek[4*g+1][tx*4];
            float4 f2 = *(const float4*)&ek[4*g+2][tx*4];
            float4 f3 = *(const float4*)&ek[4*g+3][tx*4];
            float4 w4 = *(const float4*)&wl[4*g];
            float E0[2] = {e0.x, e0.y};
            float E1[2] = {e1.x, e1.y};
            float E2[2] = {e2.x, e2.y};
            float E3[2] = {e3.x, e3.y};
            float F0[4] = {f0.x, f0.y, f0.z, f0.w};
            float F1[4] = {f1.x, f1.y, f1.z, f1.w};
            float F2[4] = {f2.x, f2.y, f2.z, f2.w};
            float F3[4] = {f3.x, f3.y, f3.z, f3.w};
            #pragma unroll
            for (int i = 0; i < 2; ++i) {
                #pragma unroll
                for (int j = 0; j < 4; ++j) {
                    float A  = fmaf(E0[i], F0[j], 1.0f);
                    float Bv = fmaf(E1[i], F1[j], 1.0f);
                    float C  = fmaf(E2[i], F2[j], 1.0f);
                    float D  = fmaf(E3[i], F3[j], 1.0f);
                    float AB = A * Bv;
                    float CD = C * D;
                    float n01 = fmaf(w4.x, Bv, w4.y * A);
                    float n23 = fmaf(w4.z, D,  w4.w * C);
                    float num = fmaf(n01, CD, n23 * AB);
                    acc[i][j] = fmaf(num, __builtin_amdgcn_rcpf(AB * CD), acc[i][j]);
                }
            }
        }
    }
    float* o = Sp + ((size_t)nh*512 + q0 + ty*2)*TK + kt*64 + tx*4;
    #pragma unroll
    for (int i = 0; i < 2; ++i) {
        float4 r = {-2.0f*acc[i][0], -2.0f*acc[i][1], -2.0f*acc[i][2], -2.0f*acc[i][3]};
        *(float4*)(o + (size_t)i*TK) = r;
    }
}

// ---------------------------------------------------------------------------
// [5] softmax over k of sum_{h<8} Sp[h]; P f32 + Ph/Pl
// ---------------------------------------------------------------------------
__global__ __launch_bounds__(256) void softmax_kernel(
    const float* __restrict__ Sp, float* __restrict__ P,
    ushort* __restrict__ Ph, ushort* __restrict__ Pl)
{
    const int lane = threadIdx.x & 63;
    const int wid  = threadIdx.x >> 6;
    const int row  = blockIdx.x * 4 + wid;
    const size_t S = (size_t)512*512;
    float v[8];
    float m = -3.4e38f;
    #pragma unroll
    for (int j = 0; j < 8; ++j) {
        int k = lane + j*64;
        float s = 0.f;
        #pragma unroll
        for (int h = 0; h < 8; ++h)
            s += Sp[h*S + (size_t)row*TK + k];
        v[j] = s;
        m = fmaxf(m, v[j]);
    }
    #pragma unroll
    for (int off = 32; off; off >>= 1) m = fmaxf(m, __shfl_xor(m, off, 64));
    float sum = 0.f;
    #pragma unroll
    for (int j = 0; j < 8; ++j) { v[j] = exp2f((v[j] - m) * LOG2EF); sum += v[j]; }
    #pragma unroll
    for (int off = 32; off; off >>= 1) sum += __shfl_xor(sum, off, 64);
    float inv = 1.0f / sum;
    #pragma unroll
    for (int j = 0; j < 8; ++j) {
        int k = lane + j*64;
        float pv = v[j] * inv;
        P[(size_t)row * TK + k] = pv;
        ushort h, l; split2(pv, h, l);
        Ph[(size_t)row * TK + k] = h;
        Pl[(size_t)row * TK + k] = l;
    }
}

// ---------------------------------------------------------------------------
// [7] Cx = sum of 4 Ep slices -> hi/lo bf16
// ---------------------------------------------------------------------------
__global__ __launch_bounds__(256) void combine_cvt_kernel(
    const float* __restrict__ Ep, ushort* __restrict__ Ch, ushort* __restrict__ Cl)
{
    int i = blockIdx.x * 256 + threadIdx.x;
    float4 p0 = ((const float4*)Ep)[i];
    float4 p1 = ((const float4*)(Ep + SLICE))[i];
    float4 p2 = ((const float4*)(Ep + 2*SLICE))[i];
    float4 p3 = ((const float4*)(Ep + 3*SLICE))[i];
    float4 s = {p0.x+p1.x+p2.x+p3.x, p0.y+p1.y+p2.y+p3.y,
                p0.z+p1.z+p2.z+p3.z, p0.w+p1.w+p2.w+p3.w};
    ushort4 hh, ll;
    split2(s.x, hh.x, ll.x); split2(s.y, hh.y, ll.y);
    split2(s.z, hh.z, ll.z); split2(s.w, hh.w, ll.w);
    ((ushort4*)Ch)[i] = hh;
    ((ushort4*)Cl)[i] = ll;
}

// ---------------------------------------------------------------------------
// [8] out-GEMM: A = [Q hi/lo | Cx hi/lo], B = Woh only (2-MFMA). K=2048/4.
// ---------------------------------------------------------------------------
__global__ __launch_bounds__(256) void mfma_out_kernel(
    const ushort* __restrict__ Qh, const ushort* __restrict__ Ql,
    const ushort* __restrict__ Cxh, const ushort* __restrict__ Cxl,
    const ushort* __restrict__ Wh,  // [1024][2048] hi
    float* __restrict__ Fp)
{
    __shared__ alignas(16) ushort lA[2][64][40];
    __shared__ alignas(16) ushort lB[64][40];
    const int t = threadIdx.x;
    const int m0 = blockIdx.y * 64, n0 = blockIdx.x * 64, kz = blockIdx.z;
    const ushort* ah_p = (kz < 2) ? Qh : Cxh;
    const ushort* al_p = (kz < 2) ? Ql : Cxl;
    const int akoff = (kz & 1) * 512;
    const int bkoff = kz * 512;
    const int srow = t >> 2, skc = (t & 3) * 8;
    const int lane = t & 63, w = t >> 6;
    const int wm = (w >> 1) * 32, wn = (w & 1) * 32;
    const int fr = lane & 15, fg = (lane >> 4) * 8;

    f32x4 acc00 = {0,0,0,0}, acc01 = {0,0,0,0}, acc10 = {0,0,0,0}, acc11 = {0,0,0,0};

    for (int kk = 0; kk < 512; kk += 32) {
        size_t aoff = (size_t)(m0+srow)*1024 + akoff + kk + skc;
        *(uint4*)&lA[0][srow][skc] = *(const uint4*)(ah_p + aoff);
        *(uint4*)&lA[1][srow][skc] = *(const uint4*)(al_p + aoff);
        *(uint4*)&lB[srow][skc] =
            *(const uint4*)(Wh + (size_t)(n0+srow)*2048 + bkoff + kk + skc);
        __syncthreads();
        bf16x8 ah0 = *(const bf16x8*)&lA[0][wm + fr     ][fg];
        bf16x8 ah1 = *(const bf16x8*)&lA[0][wm + 16 + fr][fg];
        bf16x8 al0 = *(const bf16x8*)&lA[1][wm + fr     ][fg];
        bf16x8 al1 = *(const bf16x8*)&lA[1][wm + 16 + fr][fg];
        bf16x8 bh0 = *(const bf16x8*)&lB[wn + fr     ][fg];
        bf16x8 bh1 = *(const bf16x8*)&lB[wn + 16 + fr][fg];
        acc00 = MFMA16(ah0, bh0, acc00);
        acc00 = MFMA16(al0, bh0, acc00);
        acc01 = MFMA16(ah0, bh1, acc01);
        acc01 = MFMA16(al0, bh1, acc01);
        acc10 = MFMA16(ah1, bh0, acc10);
        acc10 = MFMA16(al1, bh0, acc10);
        acc11 = MFMA16(ah1, bh1, acc11);
        acc11 = MFMA16(al1, bh1, acc11);
        __syncthreads();
    }
    float* o = Fp + (size_t)kz * SLICE;
    const int orow = (lane >> 4) * 4;
    #pragma unroll
    for (int r2 = 0; r2 < 4; ++r2) {
        o[(size_t)(m0+wm+orow+r2)*1024    + n0+wn+fr]    = acc00[r2];
        o[(size_t)(m0+wm+orow+r2)*1024    + n0+wn+16+fr] = acc01[r2];
        o[(size_t)(m0+wm+16+orow+r2)*1024 + n0+wn+fr]    = acc10[r2];
        o[(size_t)(m0+wm+16+orow+r2)*1024 + n0+wn+16+fr] = acc11[r2];
    }
}

// ---------------------------------------------------------------------------
// [9] out = tanh(sum Fp + bias)
// ---------------------------------------------------------------------------
__global__ __launch_bounds__(256) void tanh_combine_kernel(
    const float* __restrict__ Fp, const float* __restrict__ bias,
    float* __restrict__ out)
{
    int i = blockIdx.x * 256 + threadIdx.x;
    const size_t S = (size_t)B_*TQ*OS;
    float4 p0 = ((const float4*)Fp)[i];
    float4 p1 = ((const float4*)(Fp + S))[i];
    float4 p2 = ((const float4*)(Fp + 2*S))[i];
    float4 p3 = ((const float4*)(Fp + 3*S))[i];
    float4 bb = ((const float4*)bias)[i & 255];
    float4 r;
    r.x = tanhf(p0.x + p1.x + p2.x + p3.x + bb.x);
    r.y = tanhf(p0.y + p1.y + p2.y + p3.y + bb.y);
    r.z = tanhf(p0.z + p1.z + p2.z + p3.z + bb.z);
    r.w = tanhf(p0.w + p1.w + p2.w + p3.w + bb.w);
    ((float4*)out)[i] = r;
}

// ---------------------------------------------------------------------------
extern "C" void kernel_launch(void* const* d_in, const int* in_sizes, int n_in,
                              void* d_out, int out_size, void* d_ws, size_t ws_size,
                              hipStream_t stream)
{
    const float* query  = (const float*)d_in[0];
    const float* keys   = (const float*)d_in[1];
    const float* values = (const float*)d_in[2];
    const float* Wq     = (const float*)d_in[3];
    const float* bq     = (const float*)d_in[4];
    const float* watt   = (const float*)d_in[5];
    // d_in[6] = b_att: dropped (softmax shift-invariance)
    const float* Wout   = (const float*)d_in[7];
    const float* bout   = (const float*)d_in[8];

    float* out = (float*)d_out;                    // output 0 (524288 f32)
    float* P   = out + (size_t)B_*TQ*OS;           // output 1 (262144 f32)

    char* base = (char*)d_ws;
    const size_t MB = 1u << 20;
    ushort* Qh  = (ushort*)(base +  0*MB);
    ushort* Ql  = (ushort*)(base +  1*MB);
    ushort* Wqh = (ushort*)(base +  2*MB);
    ushort* Wql = (ushort*)(base +  4*MB);
    ushort* Woh = (ushort*)(base +  6*MB);   // 4 MB (hi only)
    ushort* Vth = (ushort*)(base + 10*MB);   // 4 MB (hi only)
    float*  Ap  = (float*) (base + 14*MB);   // [4][512][1024] = 8 MB
    float*  Ea  = (float*) (base + 22*MB);   // 2 MB
    float*  Sp  = (float*) (base + 24*MB);   // [8][512][512] = 8 MB
    ushort* Ph  = (ushort*)(base + 32*MB);
    ushort* Pl  = (ushort*)(base + 32*MB + 512*1024);
    float*  Ep  = (float*) (base + 33*MB);   // [4][512][1024] = 8 MB
    ushort* Cxh = (ushort*)(base + 41*MB);
    ushort* Cxl = (ushort*)(base + 42*MB);
    float*  Fp  = (float*) (base + 43*MB);   // [4][512][1024] = 8 MB

    // [1] conversions + V transpose (hi only)
    cvt_all_kernel<<<dim3(4096), dim3(256), 0, stream>>>(
        query, Wq, Wout, values, Qh, Ql, Wqh, Wql, Woh, Vth);
    // [2] A-GEMM partials: Q @ Wq^T (3-MFMA, K=1024 split 4)
    mfma_nt_kernel<<<dim3(16, 8, 4), dim3(256), 0, stream>>>(
        Qh, Ql, Wqh, Wql, Ap, 1024, 1024, 1024, 256, 0);
    // [3] Ea = exp(2*(sum Ap + bq))
    exp_combine_kernel<<<dim3(512), dim3(256), 0, stream>>>(Ap, bq, Ea);
    // [4] scores v12 (quad-rcp, 128-n per block, 8 Sp slices)
    score_v12_kernel<<<dim3(8, 8, 8), dim3(512), 0, stream>>>(Ea, keys, watt, Sp);
    // [5] softmax -> P (output 1) + Ph/Pl
    softmax_kernel<<<dim3(128), dim3(256), 0, stream>>>(Sp, P, Ph, Pl);
    // [6] PV partials: P @ V (2-MFMA, per-batch, K=512 split 4)
    mfma_nt2_kernel<<<dim3(16, 8, 4), dim3(256), 0, stream>>>(
        Ph, Pl, Vth, Ep, 512, 512, 1024, 128, VS*TK);
    // [7] Cx = sum Ep -> hi/lo bf16
    combine_cvt_kernel<<<dim3(512), dim3(256), 0, stream>>>(Ep, Cxh, Cxl);
    // [8] out-GEMM partials (2-MFMA, B hi only; K=2048 split 4)
    mfma_out_kernel<<<dim3(16, 8, 4), dim3(256), 0, stream>>>(
        Qh, Ql, Cxh, Cxl, Woh, Fp);
    // [9] out = tanh(sum + bout)
    tanh_combine_kernel<<<dim3(512), dim3(256), 0, stream>>>(Fp, bout, out);
}

// Round 18
// 78.561 us; speedup vs baseline: 1.0963x; 1.0129x over previous
//
#include <hip/hip_runtime.h>
#include <math.h>

static constexpr int B_  = 4;
static constexpr int TQ  = 128;
static constexpr int TK  = 512;
static constexpr int NN  = 1024;
static constexpr int QS  = 1024;
static constexpr int VS  = 1024;
static constexpr int OS  = 1024;

#define K2F    2.8853900817779268f   // 2*log2(e)
#define LOG2EF 1.4426950408889634f
#define SLICE  524288                // 512*1024

typedef __attribute__((ext_vector_type(8))) short bf16x8;
typedef __attribute__((ext_vector_type(4))) float f32x4;

#define MFMA16(a,b,c) __builtin_amdgcn_mfma_f32_16x16x32_bf16((a),(b),(c),0,0,0)

__device__ __forceinline__ ushort bf16_rne(float x) {
    uint u = __float_as_uint(x);
    u += 0x7FFFu + ((u >> 16) & 1u);
    return (ushort)(u >> 16);
}
__device__ __forceinline__ void split2(float x, ushort& h, ushort& l) {
    ushort hh = bf16_rne(x);
    float hv = __uint_as_float((uint)hh << 16);
    h = hh;
    l = bf16_rne(x - hv);
}

// ---------------------------------------------------------------------------
// [1] conversion: Q -> hi/lo, Wq -> hi, Wout -> hi, V transpose -> hi only
// blocks: [0,512) Q, [512,1536) Wq(hi), [1536,3584) Wout(hi), [3584,4096) V-T
// ---------------------------------------------------------------------------
__global__ __launch_bounds__(256) void cvt_all_kernel(
    const float* __restrict__ Q, const float* __restrict__ Wq,
    const float* __restrict__ Wo, const float* __restrict__ V,
    ushort* __restrict__ Qh, ushort* __restrict__ Ql,
    ushort* __restrict__ Wqh,
    ushort* __restrict__ Woh,
    ushort* __restrict__ Vth)
{
    __shared__ float tile[64][65];
    const int bid = blockIdx.x;
    const int t = threadIdx.x;
    if (bid < 3584) {
        if (bid < 512) {
            int idx = bid*256 + t;
            float4 v = ((const float4*)Q)[idx];
            ushort4 hh, ll;
            split2(v.x, hh.x, ll.x); split2(v.y, hh.y, ll.y);
            split2(v.z, hh.z, ll.z); split2(v.w, hh.w, ll.w);
            ((ushort4*)Qh)[idx] = hh;
            ((ushort4*)Ql)[idx] = ll;
        } else {
            const float* src; ushort* h; int idx;
            if (bid < 1536) { src = Wq; h = Wqh; idx = (bid-512)*256 + t; }
            else            { src = Wo; h = Woh; idx = (bid-1536)*256 + t; }
            float4 v = ((const float4*)src)[idx];
            ushort4 hh;
            hh.x = bf16_rne(v.x); hh.y = bf16_rne(v.y);
            hh.z = bf16_rne(v.z); hh.w = bf16_rne(v.w);
            ((ushort4*)h)[idx] = hh;
        }
        return;
    }
    const int vid = bid - 3584;
    const int v0 = (vid & 15) * 64;
    const int k0 = ((vid >> 4) & 7) * 64;
    const int b  = vid >> 7;
    const float* src = V + ((size_t)b*TK + k0)*VS + v0;
    #pragma unroll
    for (int p = 0; p < 4; ++p) {
        int r = (t >> 4) + p*16, c = (t & 15) * 4;
        float4 vv = *(const float4*)(src + (size_t)r*VS + c);
        tile[r][c] = vv.x; tile[r][c+1] = vv.y; tile[r][c+2] = vv.z; tile[r][c+3] = vv.w;
    }
    __syncthreads();
    ushort* dh = Vth + (size_t)b*(VS*TK) + (size_t)v0*TK + k0;
    #pragma unroll
    for (int p = 0; p < 4; ++p) {
        int vr = (t >> 4) + p*16, kc = (t & 15) * 4;
        ushort4 hh;
        hh.x = bf16_rne(tile[kc+0][vr]);
        hh.y = bf16_rne(tile[kc+1][vr]);
        hh.z = bf16_rne(tile[kc+2][vr]);
        hh.w = bf16_rne(tile[kc+3][vr]);
        *(ushort4*)(dh + (size_t)vr*TK + kc) = hh;
    }
}

// ---------------------------------------------------------------------------
// [2/6] 2-MFMA NT GEMM (A hi/lo, B hi only), M=512. A-GEMM + PV. K-split 4.
// ---------------------------------------------------------------------------
__global__ __launch_bounds__(256) void mfma_nt2_kernel(
    const ushort* __restrict__ Ah, const ushort* __restrict__ Al,
    const ushort* __restrict__ Bh,
    float* __restrict__ Cp, int lda, int ldb, int Nout, int kchunk, int bstride)
{
    __shared__ alignas(16) ushort lA[2][64][40];
    __shared__ alignas(16) ushort lB[64][40];
    const int t = threadIdx.x;
    const int m0 = blockIdx.y * 64, n0 = blockIdx.x * 64, kz = blockIdx.z;
    const int k0 = kz * kchunk;
    const int batch = m0 >> 7;
    const ushort* bhp = Bh + (size_t)batch * bstride;
    const int srow = t >> 2, skc = (t & 3) * 8;
    const int lane = t & 63, w = t >> 6;
    const int wm = (w >> 1) * 32, wn = (w & 1) * 32;
    const int fr = lane & 15, fg = (lane >> 4) * 8;

    f32x4 acc00 = {0,0,0,0}, acc01 = {0,0,0,0}, acc10 = {0,0,0,0}, acc11 = {0,0,0,0};

    for (int kb = k0; kb < k0 + kchunk; kb += 32) {
        *(uint4*)&lA[0][srow][skc] = *(const uint4*)(Ah  + (size_t)(m0+srow)*lda + kb + skc);
        *(uint4*)&lA[1][srow][skc] = *(const uint4*)(Al  + (size_t)(m0+srow)*lda + kb + skc);
        *(uint4*)&lB[srow][skc]    = *(const uint4*)(bhp + (size_t)(n0+srow)*ldb + kb + skc);
        __syncthreads();
        bf16x8 ah0 = *(const bf16x8*)&lA[0][wm + fr     ][fg];
        bf16x8 ah1 = *(const bf16x8*)&lA[0][wm + 16 + fr][fg];
        bf16x8 al0 = *(const bf16x8*)&lA[1][wm + fr     ][fg];
        bf16x8 al1 = *(const bf16x8*)&lA[1][wm + 16 + fr][fg];
        bf16x8 bh0 = *(const bf16x8*)&lB[wn + fr     ][fg];
        bf16x8 bh1 = *(const bf16x8*)&lB[wn + 16 + fr][fg];
        acc00 = MFMA16(ah0, bh0, acc00);
        acc00 = MFMA16(al0, bh0, acc00);
        acc01 = MFMA16(ah0, bh1, acc01);
        acc01 = MFMA16(al0, bh1, acc01);
        acc10 = MFMA16(ah1, bh0, acc10);
        acc10 = MFMA16(al1, bh0, acc10);
        acc11 = MFMA16(ah1, bh1, acc11);
        acc11 = MFMA16(al1, bh1, acc11);
        __syncthreads();
    }
    float* o = Cp + (size_t)kz * 512 * Nout;
    const int orow = (lane >> 4) * 4;
    #pragma unroll
    for (int r2 = 0; r2 < 4; ++r2) {
        o[(size_t)(m0+wm+orow+r2)*Nout      + n0+wn+fr]      = acc00[r2];
        o[(size_t)(m0+wm+orow+r2)*Nout      + n0+wn+16+fr]   = acc01[r2];
        o[(size_t)(m0+wm+16+orow+r2)*Nout   + n0+wn+fr]      = acc10[r2];
        o[(size_t)(m0+wm+16+orow+r2)*Nout   + n0+wn+16+fr]   = acc11[r2];
    }
}

// ---------------------------------------------------------------------------
// [3] Ea = exp2((sum of 4 Ap slices + bq) * K2F)
// ---------------------------------------------------------------------------
__global__ __launch_bounds__(256) void exp_combine_kernel(
    const float* __restrict__ Ap, const float* __restrict__ bias,
    float* __restrict__ E)
{
    int i = blockIdx.x * 256 + threadIdx.x;
    float4 p0 = ((const float4*)Ap)[i];
    float4 p1 = ((const float4*)(Ap + SLICE))[i];
    float4 p2 = ((const float4*)(Ap + 2*SLICE))[i];
    float4 p3 = ((const float4*)(Ap + 3*SLICE))[i];
    float4 bb = ((const float4*)bias)[i & 255];
    float4 r;
    r.x = exp2f((p0.x+p1.x+p2.x+p3.x+bb.x) * K2F);
    r.y = exp2f((p0.y+p1.y+p2.y+p3.y+bb.y) * K2F);
    r.z = exp2f((p0.z+p1.z+p2.z+p3.z+bb.z) * K2F);
    r.w = exp2f((p0.w+p1.w+p2.w+p3.w+bb.w) * K2F);
    ((float4*)E)[i] = r;
}

// ---------------------------------------------------------------------------
// [4] scores v12: 512-thread blocks, 64q x 64k x 128n per block (two 64-n
// staged halves, acc carried), 2x4/thread, QUAD-rcp. Grid 8x8x8 = 512 blocks.
// Sp has 8 slices (8 MB).
// ---------------------------------------------------------------------------
__global__ __launch_bounds__(512, 4) void score_v12_kernel(
    const float* __restrict__ Ea,   // [512][1024]
    const float* __restrict__ keys,
    const float* __restrict__ watt,
    float* __restrict__ Sp)         // [8][512][512]
{
    __shared__ float ea[64][66];
    __shared__ float ek[64][68];
    __shared__ float wl[64];
    const int tid = threadIdx.x;
    const int kt = blockIdx.x;      // 0..7
    const int qt = blockIdx.y;      // 0..7
    const int nh = blockIdx.z;      // 0..7
    const int q0 = qt * 64;
    const int b  = qt >> 1;
    const int k0 = b*TK + kt*64;
    const int tx = tid & 15;
    const int ty = tid >> 4;
    float acc[2][4] = {};

    #pragma unroll
    for (int half = 0; half < 2; ++half) {
        const int nbeg = nh*128 + half*64;
        if (half) __syncthreads();          // protect LDS before restage
        {   // stage ea[n][q]
            const int q = tid >> 3;
            const int nc = (tid & 7) * 8;
            const float* ep = Ea + (size_t)(q0 + q)*NN + nbeg + nc;
            float4 e0 = *(const float4*)(ep);
            float4 e1 = *(const float4*)(ep + 4);
            ea[nc+0][q] = e0.x; ea[nc+1][q] = e0.y; ea[nc+2][q] = e0.z; ea[nc+3][q] = e0.w;
            ea[nc+4][q] = e1.x; ea[nc+5][q] = e1.y; ea[nc+6][q] = e1.z; ea[nc+7][q] = e1.w;
        }
        {   // stage ek[n][k] with exp2
            const int k = tid >> 3;
            const int nc = (tid & 7) * 8;
            const float* kp = keys + (size_t)(k0 + k)*NN + nbeg + nc;
            float4 k0v = *(const float4*)(kp);
            float4 k1v = *(const float4*)(kp + 4);
            ek[nc+0][k] = exp2f(k0v.x * K2F);
            ek[nc+1][k] = exp2f(k0v.y * K2F);
            ek[nc+2][k] = exp2f(k0v.z * K2F);
            ek[nc+3][k] = exp2f(k0v.w * K2F);
            ek[nc+4][k] = exp2f(k1v.x * K2F);
            ek[nc+5][k] = exp2f(k1v.y * K2F);
            ek[nc+6][k] = exp2f(k1v.z * K2F);
            ek[nc+7][k] = exp2f(k1v.w * K2F);
        }
        if (tid < 64) wl[tid] = watt[nbeg + tid];
        __syncthreads();

        #pragma unroll 4
        for (int g = 0; g < 16; ++g) {
            float2 e0 = *(const float2*)&ea[4*g+0][ty*2];
            float2 e1 = *(const float2*)&ea[4*g+1][ty*2];
            float2 e2 = *(const float2*)&ea[4*g+2][ty*2];
            float2 e3 = *(const float2*)&ea[4*g+3][ty*2];
            float4 f0 = *(const float4*)&ek[4*g+0][tx*4];
            float4 f1 = *(const float4*)&ek[4*g+1][tx*4];
            float4 f2 = *(const float4*)&ek[4*g+2][tx*4];
            float4 f3 = *(const float4*)&ek[4*g+3][tx*4];
            float4 w4 = *(const float4*)&wl[4*g];
            float E0[2] = {e0.x, e0.y};
            float E1[2] = {e1.x, e1.y};
            float E2[2] = {e2.x, e2.y};
            float E3[2] = {e3.x, e3.y};
            float F0[4] = {f0.x, f0.y, f0.z, f0.w};
            float F1[4] = {f1.x, f1.y, f1.z, f1.w};
            float F2[4] = {f2.x, f2.y, f2.z, f2.w};
            float F3[4] = {f3.x, f3.y, f3.z, f3.w};
            #pragma unroll
            for (int i = 0; i < 2; ++i) {
                #pragma unroll
                for (int j = 0; j < 4; ++j) {
                    float A  = fmaf(E0[i], F0[j], 1.0f);
                    float Bv = fmaf(E1[i], F1[j], 1.0f);
                    float C  = fmaf(E2[i], F2[j], 1.0f);
                    float D  = fmaf(E3[i], F3[j], 1.0f);
                    float AB = A * Bv;
                    float CD = C * D;
                    float n01 = fmaf(w4.x, Bv, w4.y * A);
                    float n23 = fmaf(w4.z, D,  w4.w * C);
                    float num = fmaf(n01, CD, n23 * AB);
                    acc[i][j] = fmaf(num, __builtin_amdgcn_rcpf(AB * CD), acc[i][j]);
                }
            }
        }
    }
    float* o = Sp + ((size_t)nh*512 + q0 + ty*2)*TK + kt*64 + tx*4;
    #pragma unroll
    for (int i = 0; i < 2; ++i) {
        float4 r = {-2.0f*acc[i][0], -2.0f*acc[i][1], -2.0f*acc[i][2], -2.0f*acc[i][3]};
        *(float4*)(o + (size_t)i*TK) = r;
    }
}

// ---------------------------------------------------------------------------
// [5] softmax over k of sum_{h<8} Sp[h]; P f32 + Ph/Pl
// ---------------------------------------------------------------------------
__global__ __launch_bounds__(256) void softmax_kernel(
    const float* __restrict__ Sp, float* __restrict__ P,
    ushort* __restrict__ Ph, ushort* __restrict__ Pl)
{
    const int lane = threadIdx.x & 63;
    const int wid  = threadIdx.x >> 6;
    const int row  = blockIdx.x * 4 + wid;
    const size_t S = (size_t)512*512;
    float v[8];
    float m = -3.4e38f;
    #pragma unroll
    for (int j = 0; j < 8; ++j) {
        int k = lane + j*64;
        float s = 0.f;
        #pragma unroll
        for (int h = 0; h < 8; ++h)
            s += Sp[h*S + (size_t)row*TK + k];
        v[j] = s;
        m = fmaxf(m, v[j]);
    }
    #pragma unroll
    for (int off = 32; off; off >>= 1) m = fmaxf(m, __shfl_xor(m, off, 64));
    float sum = 0.f;
    #pragma unroll
    for (int j = 0; j < 8; ++j) { v[j] = exp2f((v[j] - m) * LOG2EF); sum += v[j]; }
    #pragma unroll
    for (int off = 32; off; off >>= 1) sum += __shfl_xor(sum, off, 64);
    float inv = 1.0f / sum;
    #pragma unroll
    for (int j = 0; j < 8; ++j) {
        int k = lane + j*64;
        float pv = v[j] * inv;
        P[(size_t)row * TK + k] = pv;
        ushort h, l; split2(pv, h, l);
        Ph[(size_t)row * TK + k] = h;
        Pl[(size_t)row * TK + k] = l;
    }
}

// ---------------------------------------------------------------------------
// [7] Cx = sum of 4 Ep slices -> hi/lo bf16
// ---------------------------------------------------------------------------
__global__ __launch_bounds__(256) void combine_cvt_kernel(
    const float* __restrict__ Ep, ushort* __restrict__ Ch, ushort* __restrict__ Cl)
{
    int i = blockIdx.x * 256 + threadIdx.x;
    float4 p0 = ((const float4*)Ep)[i];
    float4 p1 = ((const float4*)(Ep + SLICE))[i];
    float4 p2 = ((const float4*)(Ep + 2*SLICE))[i];
    float4 p3 = ((const float4*)(Ep + 3*SLICE))[i];
    float4 s = {p0.x+p1.x+p2.x+p3.x, p0.y+p1.y+p2.y+p3.y,
                p0.z+p1.z+p2.z+p3.z, p0.w+p1.w+p2.w+p3.w};
    ushort4 hh, ll;
    split2(s.x, hh.x, ll.x); split2(s.y, hh.y, ll.y);
    split2(s.z, hh.z, ll.z); split2(s.w, hh.w, ll.w);
    ((ushort4*)Ch)[i] = hh;
    ((ushort4*)Cl)[i] = ll;
}

// ---------------------------------------------------------------------------
// [8] out-GEMM: A = [Q hi/lo | Cx hi/lo], B = Woh only (2-MFMA). K=2048/4.
// ---------------------------------------------------------------------------
__global__ __launch_bounds__(256) void mfma_out_kernel(
    const ushort* __restrict__ Qh, const ushort* __restrict__ Ql,
    const ushort* __restrict__ Cxh, const ushort* __restrict__ Cxl,
    const ushort* __restrict__ Wh,  // [1024][2048] hi
    float* __restrict__ Fp)
{
    __shared__ alignas(16) ushort lA[2][64][40];
    __shared__ alignas(16) ushort lB[64][40];
    const int t = threadIdx.x;
    const int m0 = blockIdx.y * 64, n0 = blockIdx.x * 64, kz = blockIdx.z;
    const ushort* ah_p = (kz < 2) ? Qh : Cxh;
    const ushort* al_p = (kz < 2) ? Ql : Cxl;
    const int akoff = (kz & 1) * 512;
    const int bkoff = kz * 512;
    const int srow = t >> 2, skc = (t & 3) * 8;
    const int lane = t & 63, w = t >> 6;
    const int wm = (w >> 1) * 32, wn = (w & 1) * 32;
    const int fr = lane & 15, fg = (lane >> 4) * 8;

    f32x4 acc00 = {0,0,0,0}, acc01 = {0,0,0,0}, acc10 = {0,0,0,0}, acc11 = {0,0,0,0};

    for (int kk = 0; kk < 512; kk += 32) {
        size_t aoff = (size_t)(m0+srow)*1024 + akoff + kk + skc;
        *(uint4*)&lA[0][srow][skc] = *(const uint4*)(ah_p + aoff);
        *(uint4*)&lA[1][srow][skc] = *(const uint4*)(al_p + aoff);
        *(uint4*)&lB[srow][skc] =
            *(const uint4*)(Wh + (size_t)(n0+srow)*2048 + bkoff + kk + skc);
        __syncthreads();
        bf16x8 ah0 = *(const bf16x8*)&lA[0][wm + fr     ][fg];
        bf16x8 ah1 = *(const bf16x8*)&lA[0][wm + 16 + fr][fg];
        bf16x8 al0 = *(const bf16x8*)&lA[1][wm + fr     ][fg];
        bf16x8 al1 = *(const bf16x8*)&lA[1][wm + 16 + fr][fg];
        bf16x8 bh0 = *(const bf16x8*)&lB[wn + fr     ][fg];
        bf16x8 bh1 = *(const bf16x8*)&lB[wn + 16 + fr][fg];
        acc00 = MFMA16(ah0, bh0, acc00);
        acc00 = MFMA16(al0, bh0, acc00);
        acc01 = MFMA16(ah0, bh1, acc01);
        acc01 = MFMA16(al0, bh1, acc01);
        acc10 = MFMA16(ah1, bh0, acc10);
        acc10 = MFMA16(al1, bh0, acc10);
        acc11 = MFMA16(ah1, bh1, acc11);
        acc11 = MFMA16(al1, bh1, acc11);
        __syncthreads();
    }
    float* o = Fp + (size_t)kz * SLICE;
    const int orow = (lane >> 4) * 4;
    #pragma unroll
    for (int r2 = 0; r2 < 4; ++r2) {
        o[(size_t)(m0+wm+orow+r2)*1024    + n0+wn+fr]    = acc00[r2];
        o[(size_t)(m0+wm+orow+r2)*1024    + n0+wn+16+fr] = acc01[r2];
        o[(size_t)(m0+wm+16+orow+r2)*1024 + n0+wn+fr]    = acc10[r2];
        o[(size_t)(m0+wm+16+orow+r2)*1024 + n0+wn+16+fr] = acc11[r2];
    }
}

// ---------------------------------------------------------------------------
// [9] out = tanh(sum Fp + bias)
// ---------------------------------------------------------------------------
__global__ __launch_bounds__(256) void tanh_combine_kernel(
    const float* __restrict__ Fp, const float* __restrict__ bias,
    float* __restrict__ out)
{
    int i = blockIdx.x * 256 + threadIdx.x;
    const size_t S = (size_t)B_*TQ*OS;
    float4 p0 = ((const float4*)Fp)[i];
    float4 p1 = ((const float4*)(Fp + S))[i];
    float4 p2 = ((const float4*)(Fp + 2*S))[i];
    float4 p3 = ((const float4*)(Fp + 3*S))[i];
    float4 bb = ((const float4*)bias)[i & 255];
    float4 r;
    r.x = tanhf(p0.x + p1.x + p2.x + p3.x + bb.x);
    r.y = tanhf(p0.y + p1.y + p2.y + p3.y + bb.y);
    r.z = tanhf(p0.z + p1.z + p2.z + p3.z + bb.z);
    r.w = tanhf(p0.w + p1.w + p2.w + p3.w + bb.w);
    ((float4*)out)[i] = r;
}

// ---------------------------------------------------------------------------
extern "C" void kernel_launch(void* const* d_in, const int* in_sizes, int n_in,
                              void* d_out, int out_size, void* d_ws, size_t ws_size,
                              hipStream_t stream)
{
    const float* query  = (const float*)d_in[0];
    const float* keys   = (const float*)d_in[1];
    const float* values = (const float*)d_in[2];
    const float* Wq     = (const float*)d_in[3];
    const float* bq     = (const float*)d_in[4];
    const float* watt   = (const float*)d_in[5];
    // d_in[6] = b_att: dropped (softmax shift-invariance)
    const float* Wout   = (const float*)d_in[7];
    const float* bout   = (const float*)d_in[8];

    float* out = (float*)d_out;                    // output 0 (524288 f32)
    float* P   = out + (size_t)B_*TQ*OS;           // output 1 (262144 f32)

    char* base = (char*)d_ws;
    const size_t MB = 1u << 20;
    ushort* Qh  = (ushort*)(base +  0*MB);
    ushort* Ql  = (ushort*)(base +  1*MB);
    ushort* Wqh = (ushort*)(base +  2*MB);   // 2 MB (hi only)
    ushort* Woh = (ushort*)(base +  6*MB);   // 4 MB (hi only)
    ushort* Vth = (ushort*)(base + 10*MB);   // 4 MB (hi only)
    float*  Ap  = (float*) (base + 14*MB);   // [4][512][1024] = 8 MB
    float*  Ea  = (float*) (base + 22*MB);   // 2 MB
    float*  Sp  = (float*) (base + 24*MB);   // [8][512][512] = 8 MB
    ushort* Ph  = (ushort*)(base + 32*MB);
    ushort* Pl  = (ushort*)(base + 32*MB + 512*1024);
    float*  Ep  = (float*) (base + 33*MB);   // [4][512][1024] = 8 MB
    ushort* Cxh = (ushort*)(base + 41*MB);
    ushort* Cxl = (ushort*)(base + 42*MB);
    float*  Fp  = (float*) (base + 43*MB);   // [4][512][1024] = 8 MB

    // [1] conversions + V transpose (Wq/Wout/V hi-only; Q hi/lo)
    cvt_all_kernel<<<dim3(4096), dim3(256), 0, stream>>>(
        query, Wq, Wout, values, Qh, Ql, Wqh, Woh, Vth);
    // [2] A-GEMM partials: Q @ Wq^T (2-MFMA, B hi only; K=1024 split 4)
    mfma_nt2_kernel<<<dim3(16, 8, 4), dim3(256), 0, stream>>>(
        Qh, Ql, Wqh, Ap, 1024, 1024, 1024, 256, 0);
    // [3] Ea = exp(2*(sum Ap + bq))
    exp_combine_kernel<<<dim3(512), dim3(256), 0, stream>>>(Ap, bq, Ea);
    // [4] scores v12 (quad-rcp, 128-n per block, 8 Sp slices)
    score_v12_kernel<<<dim3(8, 8, 8), dim3(512), 0, stream>>>(Ea, keys, watt, Sp);
    // [5] softmax -> P (output 1) + Ph/Pl
    softmax_kernel<<<dim3(128), dim3(256), 0, stream>>>(Sp, P, Ph, Pl);
    // [6] PV partials: P @ V (2-MFMA, per-batch, K=512 split 4)
    mfma_nt2_kernel<<<dim3(16, 8, 4), dim3(256), 0, stream>>>(
        Ph, Pl, Vth, Ep, 512, 512, 1024, 128, VS*TK);
    // [7] Cx = sum Ep -> hi/lo bf16
    combine_cvt_kernel<<<dim3(512), dim3(256), 0, stream>>>(Ep, Cxh, Cxl);
    // [8] out-GEMM partials (2-MFMA, B hi only; K=2048 split 4)
    mfma_out_kernel<<<dim3(16, 8, 4), dim3(256), 0, stream>>>(
        Qh, Ql, Cxh, Cxl, Woh, Fp);
    // [9] out = tanh(sum + bout)
    tanh_combine_kernel<<<dim3(512), dim3(256), 0, stream>>>(Fp, bout, out);
}

// Round 19
// 73.772 us; speedup vs baseline: 1.1675x; 1.0649x over previous
//
#include <hip/hip_runtime.h>
#include <math.h>

static constexpr int B_  = 4;
static constexpr int TQ  = 128;
static constexpr int TK  = 512;
static constexpr int NN  = 1024;
static constexpr int QS  = 1024;
static constexpr int VS  = 1024;
static constexpr int OS  = 1024;

#define K2F    2.8853900817779268f   // 2*log2(e)
#define LOG2EF 1.4426950408889634f
#define SLICE  524288                // 512*1024

typedef __attribute__((ext_vector_type(8))) short bf16x8;
typedef __attribute__((ext_vector_type(4))) float f32x4;

#define MFMA16(a,b,c) __builtin_amdgcn_mfma_f32_16x16x32_bf16((a),(b),(c),0,0,0)

__device__ __forceinline__ ushort bf16_rne(float x) {
    uint u = __float_as_uint(x);
    u += 0x7FFFu + ((u >> 16) & 1u);
    return (ushort)(u >> 16);
}
__device__ __forceinline__ void split2(float x, ushort& h, ushort& l) {
    ushort hh = bf16_rne(x);
    float hv = __uint_as_float((uint)hh << 16);
    h = hh;
    l = bf16_rne(x - hv);
}

// ---------------------------------------------------------------------------
// [1] conversion: Q -> hi/lo, Wq -> hi, Wout -> hi, V transpose -> hi only
// blocks: [0,512) Q, [512,1536) Wq(hi), [1536,3584) Wout(hi), [3584,4096) V-T
// ---------------------------------------------------------------------------
__global__ __launch_bounds__(256) void cvt_all_kernel(
    const float* __restrict__ Q, const float* __restrict__ Wq,
    const float* __restrict__ Wo, const float* __restrict__ V,
    ushort* __restrict__ Qh, ushort* __restrict__ Ql,
    ushort* __restrict__ Wqh,
    ushort* __restrict__ Woh,
    ushort* __restrict__ Vth)
{
    __shared__ float tile[64][65];
    const int bid = blockIdx.x;
    const int t = threadIdx.x;
    if (bid < 3584) {
        if (bid < 512) {
            int idx = bid*256 + t;
            float4 v = ((const float4*)Q)[idx];
            ushort4 hh, ll;
            split2(v.x, hh.x, ll.x); split2(v.y, hh.y, ll.y);
            split2(v.z, hh.z, ll.z); split2(v.w, hh.w, ll.w);
            ((ushort4*)Qh)[idx] = hh;
            ((ushort4*)Ql)[idx] = ll;
        } else {
            const float* src; ushort* h; int idx;
            if (bid < 1536) { src = Wq; h = Wqh; idx = (bid-512)*256 + t; }
            else            { src = Wo; h = Woh; idx = (bid-1536)*256 + t; }
            float4 v = ((const float4*)src)[idx];
            ushort4 hh;
            hh.x = bf16_rne(v.x); hh.y = bf16_rne(v.y);
            hh.z = bf16_rne(v.z); hh.w = bf16_rne(v.w);
            ((ushort4*)h)[idx] = hh;
        }
        return;
    }
    const int vid = bid - 3584;
    const int v0 = (vid & 15) * 64;
    const int k0 = ((vid >> 4) & 7) * 64;
    const int b  = vid >> 7;
    const float* src = V + ((size_t)b*TK + k0)*VS + v0;
    #pragma unroll
    for (int p = 0; p < 4; ++p) {
        int r = (t >> 4) + p*16, c = (t & 15) * 4;
        float4 vv = *(const float4*)(src + (size_t)r*VS + c);
        tile[r][c] = vv.x; tile[r][c+1] = vv.y; tile[r][c+2] = vv.z; tile[r][c+3] = vv.w;
    }
    __syncthreads();
    ushort* dh = Vth + (size_t)b*(VS*TK) + (size_t)v0*TK + k0;
    #pragma unroll
    for (int p = 0; p < 4; ++p) {
        int vr = (t >> 4) + p*16, kc = (t & 15) * 4;
        ushort4 hh;
        hh.x = bf16_rne(tile[kc+0][vr]);
        hh.y = bf16_rne(tile[kc+1][vr]);
        hh.z = bf16_rne(tile[kc+2][vr]);
        hh.w = bf16_rne(tile[kc+3][vr]);
        *(ushort4*)(dh + (size_t)vr*TK + kc) = hh;
    }
}

// ---------------------------------------------------------------------------
// [2] 2-MFMA NT GEMM (A hi/lo, B hi only), M=512. A-GEMM only (score path
// keeps full A precision). K-split 4.
// ---------------------------------------------------------------------------
__global__ __launch_bounds__(256) void mfma_nt2_kernel(
    const ushort* __restrict__ Ah, const ushort* __restrict__ Al,
    const ushort* __restrict__ Bh,
    float* __restrict__ Cp, int lda, int ldb, int Nout, int kchunk, int bstride)
{
    __shared__ alignas(16) ushort lA[2][64][40];
    __shared__ alignas(16) ushort lB[64][40];
    const int t = threadIdx.x;
    const int m0 = blockIdx.y * 64, n0 = blockIdx.x * 64, kz = blockIdx.z;
    const int k0 = kz * kchunk;
    const int batch = m0 >> 7;
    const ushort* bhp = Bh + (size_t)batch * bstride;
    const int srow = t >> 2, skc = (t & 3) * 8;
    const int lane = t & 63, w = t >> 6;
    const int wm = (w >> 1) * 32, wn = (w & 1) * 32;
    const int fr = lane & 15, fg = (lane >> 4) * 8;

    f32x4 acc00 = {0,0,0,0}, acc01 = {0,0,0,0}, acc10 = {0,0,0,0}, acc11 = {0,0,0,0};

    for (int kb = k0; kb < k0 + kchunk; kb += 32) {
        *(uint4*)&lA[0][srow][skc] = *(const uint4*)(Ah  + (size_t)(m0+srow)*lda + kb + skc);
        *(uint4*)&lA[1][srow][skc] = *(const uint4*)(Al  + (size_t)(m0+srow)*lda + kb + skc);
        *(uint4*)&lB[srow][skc]    = *(const uint4*)(bhp + (size_t)(n0+srow)*ldb + kb + skc);
        __syncthreads();
        bf16x8 ah0 = *(const bf16x8*)&lA[0][wm + fr     ][fg];
        bf16x8 ah1 = *(const bf16x8*)&lA[0][wm + 16 + fr][fg];
        bf16x8 al0 = *(const bf16x8*)&lA[1][wm + fr     ][fg];
        bf16x8 al1 = *(const bf16x8*)&lA[1][wm + 16 + fr][fg];
        bf16x8 bh0 = *(const bf16x8*)&lB[wn + fr     ][fg];
        bf16x8 bh1 = *(const bf16x8*)&lB[wn + 16 + fr][fg];
        acc00 = MFMA16(ah0, bh0, acc00);
        acc00 = MFMA16(al0, bh0, acc00);
        acc01 = MFMA16(ah0, bh1, acc01);
        acc01 = MFMA16(al0, bh1, acc01);
        acc10 = MFMA16(ah1, bh0, acc10);
        acc10 = MFMA16(al1, bh0, acc10);
        acc11 = MFMA16(ah1, bh1, acc11);
        acc11 = MFMA16(al1, bh1, acc11);
        __syncthreads();
    }
    float* o = Cp + (size_t)kz * 512 * Nout;
    const int orow = (lane >> 4) * 4;
    #pragma unroll
    for (int r2 = 0; r2 < 4; ++r2) {
        o[(size_t)(m0+wm+orow+r2)*Nout      + n0+wn+fr]      = acc00[r2];
        o[(size_t)(m0+wm+orow+r2)*Nout      + n0+wn+16+fr]   = acc01[r2];
        o[(size_t)(m0+wm+16+orow+r2)*Nout   + n0+wn+fr]      = acc10[r2];
        o[(size_t)(m0+wm+16+orow+r2)*Nout   + n0+wn+16+fr]   = acc11[r2];
    }
}

// ---------------------------------------------------------------------------
// [6] 1-MFMA plain-bf16 NT GEMM (A hi, B hi), M=512. PV. K-split 4.
// ---------------------------------------------------------------------------
__global__ __launch_bounds__(256) void mfma_nt1_kernel(
    const ushort* __restrict__ Ah,
    const ushort* __restrict__ Bh,
    float* __restrict__ Cp, int lda, int ldb, int Nout, int kchunk, int bstride)
{
    __shared__ alignas(16) ushort lA[64][40];
    __shared__ alignas(16) ushort lB[64][40];
    const int t = threadIdx.x;
    const int m0 = blockIdx.y * 64, n0 = blockIdx.x * 64, kz = blockIdx.z;
    const int k0 = kz * kchunk;
    const int batch = m0 >> 7;
    const ushort* bhp = Bh + (size_t)batch * bstride;
    const int srow = t >> 2, skc = (t & 3) * 8;
    const int lane = t & 63, w = t >> 6;
    const int wm = (w >> 1) * 32, wn = (w & 1) * 32;
    const int fr = lane & 15, fg = (lane >> 4) * 8;

    f32x4 acc00 = {0,0,0,0}, acc01 = {0,0,0,0}, acc10 = {0,0,0,0}, acc11 = {0,0,0,0};

    for (int kb = k0; kb < k0 + kchunk; kb += 32) {
        *(uint4*)&lA[srow][skc] = *(const uint4*)(Ah  + (size_t)(m0+srow)*lda + kb + skc);
        *(uint4*)&lB[srow][skc] = *(const uint4*)(bhp + (size_t)(n0+srow)*ldb + kb + skc);
        __syncthreads();
        bf16x8 ah0 = *(const bf16x8*)&lA[wm + fr     ][fg];
        bf16x8 ah1 = *(const bf16x8*)&lA[wm + 16 + fr][fg];
        bf16x8 bh0 = *(const bf16x8*)&lB[wn + fr     ][fg];
        bf16x8 bh1 = *(const bf16x8*)&lB[wn + 16 + fr][fg];
        acc00 = MFMA16(ah0, bh0, acc00);
        acc01 = MFMA16(ah0, bh1, acc01);
        acc10 = MFMA16(ah1, bh0, acc10);
        acc11 = MFMA16(ah1, bh1, acc11);
        __syncthreads();
    }
    float* o = Cp + (size_t)kz * 512 * Nout;
    const int orow = (lane >> 4) * 4;
    #pragma unroll
    for (int r2 = 0; r2 < 4; ++r2) {
        o[(size_t)(m0+wm+orow+r2)*Nout      + n0+wn+fr]      = acc00[r2];
        o[(size_t)(m0+wm+orow+r2)*Nout      + n0+wn+16+fr]   = acc01[r2];
        o[(size_t)(m0+wm+16+orow+r2)*Nout   + n0+wn+fr]      = acc10[r2];
        o[(size_t)(m0+wm+16+orow+r2)*Nout   + n0+wn+16+fr]   = acc11[r2];
    }
}

// ---------------------------------------------------------------------------
// [3] Ea = exp2((sum of 4 Ap slices + bq) * K2F)
// ---------------------------------------------------------------------------
__global__ __launch_bounds__(256) void exp_combine_kernel(
    const float* __restrict__ Ap, const float* __restrict__ bias,
    float* __restrict__ E)
{
    int i = blockIdx.x * 256 + threadIdx.x;
    float4 p0 = ((const float4*)Ap)[i];
    float4 p1 = ((const float4*)(Ap + SLICE))[i];
    float4 p2 = ((const float4*)(Ap + 2*SLICE))[i];
    float4 p3 = ((const float4*)(Ap + 3*SLICE))[i];
    float4 bb = ((const float4*)bias)[i & 255];
    float4 r;
    r.x = exp2f((p0.x+p1.x+p2.x+p3.x+bb.x) * K2F);
    r.y = exp2f((p0.y+p1.y+p2.y+p3.y+bb.y) * K2F);
    r.z = exp2f((p0.z+p1.z+p2.z+p3.z+bb.z) * K2F);
    r.w = exp2f((p0.w+p1.w+p2.w+p3.w+bb.w) * K2F);
    ((float4*)E)[i] = r;
}

// ---------------------------------------------------------------------------
// [4] scores v12: 512-thread blocks, 64q x 64k x 128n per block (two 64-n
// staged halves, acc carried), 2x4/thread, QUAD-rcp. Grid 8x8x8 = 512 blocks.
// ---------------------------------------------------------------------------
__global__ __launch_bounds__(512, 4) void score_v12_kernel(
    const float* __restrict__ Ea,   // [512][1024]
    const float* __restrict__ keys,
    const float* __restrict__ watt,
    float* __restrict__ Sp)         // [8][512][512]
{
    __shared__ float ea[64][66];
    __shared__ float ek[64][68];
    __shared__ float wl[64];
    const int tid = threadIdx.x;
    const int kt = blockIdx.x;      // 0..7
    const int qt = blockIdx.y;      // 0..7
    const int nh = blockIdx.z;      // 0..7
    const int q0 = qt * 64;
    const int b  = qt >> 1;
    const int k0 = b*TK + kt*64;
    const int tx = tid & 15;
    const int ty = tid >> 4;
    float acc[2][4] = {};

    #pragma unroll
    for (int half = 0; half < 2; ++half) {
        const int nbeg = nh*128 + half*64;
        if (half) __syncthreads();
        {   // stage ea[n][q]
            const int q = tid >> 3;
            const int nc = (tid & 7) * 8;
            const float* ep = Ea + (size_t)(q0 + q)*NN + nbeg + nc;
            float4 e0 = *(const float4*)(ep);
            float4 e1 = *(const float4*)(ep + 4);
            ea[nc+0][q] = e0.x; ea[nc+1][q] = e0.y; ea[nc+2][q] = e0.z; ea[nc+3][q] = e0.w;
            ea[nc+4][q] = e1.x; ea[nc+5][q] = e1.y; ea[nc+6][q] = e1.z; ea[nc+7][q] = e1.w;
        }
        {   // stage ek[n][k] with exp2
            const int k = tid >> 3;
            const int nc = (tid & 7) * 8;
            const float* kp = keys + (size_t)(k0 + k)*NN + nbeg + nc;
            float4 k0v = *(const float4*)(kp);
            float4 k1v = *(const float4*)(kp + 4);
            ek[nc+0][k] = exp2f(k0v.x * K2F);
            ek[nc+1][k] = exp2f(k0v.y * K2F);
            ek[nc+2][k] = exp2f(k0v.z * K2F);
            ek[nc+3][k] = exp2f(k0v.w * K2F);
            ek[nc+4][k] = exp2f(k1v.x * K2F);
            ek[nc+5][k] = exp2f(k1v.y * K2F);
            ek[nc+6][k] = exp2f(k1v.z * K2F);
            ek[nc+7][k] = exp2f(k1v.w * K2F);
        }
        if (tid < 64) wl[tid] = watt[nbeg + tid];
        __syncthreads();

        #pragma unroll 4
        for (int g = 0; g < 16; ++g) {
            float2 e0 = *(const float2*)&ea[4*g+0][ty*2];
            float2 e1 = *(const float2*)&ea[4*g+1][ty*2];
            float2 e2 = *(const float2*)&ea[4*g+2][ty*2];
            float2 e3 = *(const float2*)&ea[4*g+3][ty*2];
            float4 f0 = *(const float4*)&ek[4*g+0][tx*4];
            float4 f1 = *(const float4*)&ek[4*g+1][tx*4];
            float4 f2 = *(const float4*)&ek[4*g+2][tx*4];
            float4 f3 = *(const float4*)&ek[4*g+3][tx*4];
            float4 w4 = *(const float4*)&wl[4*g];
            float E0[2] = {e0.x, e0.y};
            float E1[2] = {e1.x, e1.y};
            float E2[2] = {e2.x, e2.y};
            float E3[2] = {e3.x, e3.y};
            float F0[4] = {f0.x, f0.y, f0.z, f0.w};
            float F1[4] = {f1.x, f1.y, f1.z, f1.w};
            float F2[4] = {f2.x, f2.y, f2.z, f2.w};
            float F3[4] = {f3.x, f3.y, f3.z, f3.w};
            #pragma unroll
            for (int i = 0; i < 2; ++i) {
                #pragma unroll
                for (int j = 0; j < 4; ++j) {
                    float A  = fmaf(E0[i], F0[j], 1.0f);
                    float Bv = fmaf(E1[i], F1[j], 1.0f);
                    float C  = fmaf(E2[i], F2[j], 1.0f);
                    float D  = fmaf(E3[i], F3[j], 1.0f);
                    float AB = A * Bv;
                    float CD = C * D;
                    float n01 = fmaf(w4.x, Bv, w4.y * A);
                    float n23 = fmaf(w4.z, D,  w4.w * C);
                    float num = fmaf(n01, CD, n23 * AB);
                    acc[i][j] = fmaf(num, __builtin_amdgcn_rcpf(AB * CD), acc[i][j]);
                }
            }
        }
    }
    float* o = Sp + ((size_t)nh*512 + q0 + ty*2)*TK + kt*64 + tx*4;
    #pragma unroll
    for (int i = 0; i < 2; ++i) {
        float4 r = {-2.0f*acc[i][0], -2.0f*acc[i][1], -2.0f*acc[i][2], -2.0f*acc[i][3]};
        *(float4*)(o + (size_t)i*TK) = r;
    }
}

// ---------------------------------------------------------------------------
// [5] softmax over k of sum_{h<8} Sp[h]; P f32 (output 1) + Ph (bf16)
// ---------------------------------------------------------------------------
__global__ __launch_bounds__(256) void softmax_kernel(
    const float* __restrict__ Sp, float* __restrict__ P,
    ushort* __restrict__ Ph)
{
    const int lane = threadIdx.x & 63;
    const int wid  = threadIdx.x >> 6;
    const int row  = blockIdx.x * 4 + wid;
    const size_t S = (size_t)512*512;
    float v[8];
    float m = -3.4e38f;
    #pragma unroll
    for (int j = 0; j < 8; ++j) {
        int k = lane + j*64;
        float s = 0.f;
        #pragma unroll
        for (int h = 0; h < 8; ++h)
            s += Sp[h*S + (size_t)row*TK + k];
        v[j] = s;
        m = fmaxf(m, v[j]);
    }
    #pragma unroll
    for (int off = 32; off; off >>= 1) m = fmaxf(m, __shfl_xor(m, off, 64));
    float sum = 0.f;
    #pragma unroll
    for (int j = 0; j < 8; ++j) { v[j] = exp2f((v[j] - m) * LOG2EF); sum += v[j]; }
    #pragma unroll
    for (int off = 32; off; off >>= 1) sum += __shfl_xor(sum, off, 64);
    float inv = 1.0f / sum;
    #pragma unroll
    for (int j = 0; j < 8; ++j) {
        int k = lane + j*64;
        float pv = v[j] * inv;
        P[(size_t)row * TK + k] = pv;
        Ph[(size_t)row * TK + k] = bf16_rne(pv);
    }
}

// ---------------------------------------------------------------------------
// [7] Cx = sum of 4 Ep slices -> hi bf16 only
// ---------------------------------------------------------------------------
__global__ __launch_bounds__(256) void combine_cvt_kernel(
    const float* __restrict__ Ep, ushort* __restrict__ Ch)
{
    int i = blockIdx.x * 256 + threadIdx.x;
    float4 p0 = ((const float4*)Ep)[i];
    float4 p1 = ((const float4*)(Ep + SLICE))[i];
    float4 p2 = ((const float4*)(Ep + 2*SLICE))[i];
    float4 p3 = ((const float4*)(Ep + 3*SLICE))[i];
    float4 s = {p0.x+p1.x+p2.x+p3.x, p0.y+p1.y+p2.y+p3.y,
                p0.z+p1.z+p2.z+p3.z, p0.w+p1.w+p2.w+p3.w};
    ushort4 hh;
    hh.x = bf16_rne(s.x); hh.y = bf16_rne(s.y);
    hh.z = bf16_rne(s.z); hh.w = bf16_rne(s.w);
    ((ushort4*)Ch)[i] = hh;
}

// ---------------------------------------------------------------------------
// [8] out-GEMM: A = [Qh | Cxh] (hi only), B = Woh (1-MFMA). K=2048/4.
// ---------------------------------------------------------------------------
__global__ __launch_bounds__(256) void mfma_out_kernel(
    const ushort* __restrict__ Qh,
    const ushort* __restrict__ Cxh,
    const ushort* __restrict__ Wh,  // [1024][2048] hi
    float* __restrict__ Fp)
{
    __shared__ alignas(16) ushort lA[64][40];
    __shared__ alignas(16) ushort lB[64][40];
    const int t = threadIdx.x;
    const int m0 = blockIdx.y * 64, n0 = blockIdx.x * 64, kz = blockIdx.z;
    const ushort* ah_p = (kz < 2) ? Qh : Cxh;
    const int akoff = (kz & 1) * 512;
    const int bkoff = kz * 512;
    const int srow = t >> 2, skc = (t & 3) * 8;
    const int lane = t & 63, w = t >> 6;
    const int wm = (w >> 1) * 32, wn = (w & 1) * 32;
    const int fr = lane & 15, fg = (lane >> 4) * 8;

    f32x4 acc00 = {0,0,0,0}, acc01 = {0,0,0,0}, acc10 = {0,0,0,0}, acc11 = {0,0,0,0};

    for (int kk = 0; kk < 512; kk += 32) {
        size_t aoff = (size_t)(m0+srow)*1024 + akoff + kk + skc;
        *(uint4*)&lA[srow][skc] = *(const uint4*)(ah_p + aoff);
        *(uint4*)&lB[srow][skc] =
            *(const uint4*)(Wh + (size_t)(n0+srow)*2048 + bkoff + kk + skc);
        __syncthreads();
        bf16x8 ah0 = *(const bf16x8*)&lA[wm + fr     ][fg];
        bf16x8 ah1 = *(const bf16x8*)&lA[wm + 16 + fr][fg];
        bf16x8 bh0 = *(const bf16x8*)&lB[wn + fr     ][fg];
        bf16x8 bh1 = *(const bf16x8*)&lB[wn + 16 + fr][fg];
        acc00 = MFMA16(ah0, bh0, acc00);
        acc01 = MFMA16(ah0, bh1, acc01);
        acc10 = MFMA16(ah1, bh0, acc10);
        acc11 = MFMA16(ah1, bh1, acc11);
        __syncthreads();
    }
    float* o = Fp + (size_t)kz * SLICE;
    const int orow = (lane >> 4) * 4;
    #pragma unroll
    for (int r2 = 0; r2 < 4; ++r2) {
        o[(size_t)(m0+wm+orow+r2)*1024    + n0+wn+fr]    = acc00[r2];
        o[(size_t)(m0+wm+orow+r2)*1024    + n0+wn+16+fr] = acc01[r2];
        o[(size_t)(m0+wm+16+orow+r2)*1024 + n0+wn+fr]    = acc10[r2];
        o[(size_t)(m0+wm+16+orow+r2)*1024 + n0+wn+16+fr] = acc11[r2];
    }
}

// ---------------------------------------------------------------------------
// [9] out = tanh(sum Fp + bias)
// ---------------------------------------------------------------------------
__global__ __launch_bounds__(256) void tanh_combine_kernel(
    const float* __restrict__ Fp, const float* __restrict__ bias,
    float* __restrict__ out)
{
    int i = blockIdx.x * 256 + threadIdx.x;
    const size_t S = (size_t)B_*TQ*OS;
    float4 p0 = ((const float4*)Fp)[i];
    float4 p1 = ((const float4*)(Fp + S))[i];
    float4 p2 = ((const float4*)(Fp + 2*S))[i];
    float4 p3 = ((const float4*)(Fp + 3*S))[i];
    float4 bb = ((const float4*)bias)[i & 255];
    float4 r;
    r.x = tanhf(p0.x + p1.x + p2.x + p3.x + bb.x);
    r.y = tanhf(p0.y + p1.y + p2.y + p3.y + bb.y);
    r.z = tanhf(p0.z + p1.z + p2.z + p3.z + bb.z);
    r.w = tanhf(p0.w + p1.w + p2.w + p3.w + bb.w);
    ((float4*)out)[i] = r;
}

// ---------------------------------------------------------------------------
extern "C" void kernel_launch(void* const* d_in, const int* in_sizes, int n_in,
                              void* d_out, int out_size, void* d_ws, size_t ws_size,
                              hipStream_t stream)
{
    const float* query  = (const float*)d_in[0];
    const float* keys   = (const float*)d_in[1];
    const float* values = (const float*)d_in[2];
    const float* Wq     = (const float*)d_in[3];
    const float* bq     = (const float*)d_in[4];
    const float* watt   = (const float*)d_in[5];
    // d_in[6] = b_att: dropped (softmax shift-invariance)
    const float* Wout   = (const float*)d_in[7];
    const float* bout   = (const float*)d_in[8];

    float* out = (float*)d_out;                    // output 0 (524288 f32)
    float* P   = out + (size_t)B_*TQ*OS;           // output 1 (262144 f32)

    char* base = (char*)d_ws;
    const size_t MB = 1u << 20;
    ushort* Qh  = (ushort*)(base +  0*MB);
    ushort* Ql  = (ushort*)(base +  1*MB);
    ushort* Wqh = (ushort*)(base +  2*MB);   // 2 MB (hi only)
    ushort* Woh = (ushort*)(base +  6*MB);   // 4 MB (hi only)
    ushort* Vth = (ushort*)(base + 10*MB);   // 4 MB (hi only)
    float*  Ap  = (float*) (base + 14*MB);   // [4][512][1024] = 8 MB
    float*  Ea  = (float*) (base + 22*MB);   // 2 MB
    float*  Sp  = (float*) (base + 24*MB);   // [8][512][512] = 8 MB
    ushort* Ph  = (ushort*)(base + 32*MB);   // 0.5 MB (hi only)
    float*  Ep  = (float*) (base + 33*MB);   // [4][512][1024] = 8 MB
    ushort* Cxh = (ushort*)(base + 41*MB);   // 1 MB (hi only)
    float*  Fp  = (float*) (base + 43*MB);   // [4][512][1024] = 8 MB

    // [1] conversions + V transpose (Wq/Wout/V hi-only; Q hi/lo)
    cvt_all_kernel<<<dim3(4096), dim3(256), 0, stream>>>(
        query, Wq, Wout, values, Qh, Ql, Wqh, Woh, Vth);
    // [2] A-GEMM partials: Q @ Wq^T (2-MFMA, A hi/lo; K=1024 split 4)
    mfma_nt2_kernel<<<dim3(16, 8, 4), dim3(256), 0, stream>>>(
        Qh, Ql, Wqh, Ap, 1024, 1024, 1024, 256, 0);
    // [3] Ea = exp(2*(sum Ap + bq))
    exp_combine_kernel<<<dim3(512), dim3(256), 0, stream>>>(Ap, bq, Ea);
    // [4] scores v12 (quad-rcp, 128-n per block, 8 Sp slices)
    score_v12_kernel<<<dim3(8, 8, 8), dim3(512), 0, stream>>>(Ea, keys, watt, Sp);
    // [5] softmax -> P (output 1) + Ph (bf16 hi)
    softmax_kernel<<<dim3(128), dim3(256), 0, stream>>>(Sp, P, Ph);
    // [6] PV partials: P @ V (1-MFMA bf16, per-batch, K=512 split 4)
    mfma_nt1_kernel<<<dim3(16, 8, 4), dim3(256), 0, stream>>>(
        Ph, Vth, Ep, 512, 512, 1024, 128, VS*TK);
    // [7] Cx = sum Ep -> hi bf16
    combine_cvt_kernel<<<dim3(512), dim3(256), 0, stream>>>(Ep, Cxh);
    // [8] out-GEMM partials (1-MFMA bf16; K=2048 split 4)
    mfma_out_kernel<<<dim3(16, 8, 4), dim3(256), 0, stream>>>(
        Qh, Cxh, Woh, Fp);
    // [9] out = tanh(sum + bout)
    tanh_combine_kernel<<<dim3(512), dim3(256), 0, stream>>>(Fp, bout, out);
}

// Round 20
// 73.187 us; speedup vs baseline: 1.1768x; 1.0080x over previous
//
#include <hip/hip_runtime.h>
#include <math.h>

static constexpr int B_  = 4;
static constexpr int TQ  = 128;
static constexpr int TK  = 512;
static constexpr int NN  = 1024;
static constexpr int QS  = 1024;
static constexpr int VS  = 1024;
static constexpr int OS  = 1024;

#define K2F    2.8853900817779268f   // 2*log2(e)
#define LOG2EF 1.4426950408889634f
#define SLICE  524288                // 512*1024

typedef __attribute__((ext_vector_type(8))) short bf16x8;
typedef __attribute__((ext_vector_type(4))) float f32x4;

#define MFMA16(a,b,c) __builtin_amdgcn_mfma_f32_16x16x32_bf16((a),(b),(c),0,0,0)

__device__ __forceinline__ ushort bf16_rne(float x) {
    uint u = __float_as_uint(x);
    u += 0x7FFFu + ((u >> 16) & 1u);
    return (ushort)(u >> 16);
}
__device__ __forceinline__ void split2(float x, ushort& h, ushort& l) {
    ushort hh = bf16_rne(x);
    float hv = __uint_as_float((uint)hh << 16);
    h = hh;
    l = bf16_rne(x - hv);
}

// ---------------------------------------------------------------------------
// [1] conversion: Q -> hi/lo, Wq -> hi, Wout -> hi, V transpose -> hi only
// blocks: [0,512) Q, [512,1536) Wq(hi), [1536,3584) Wout(hi), [3584,4096) V-T
// ---------------------------------------------------------------------------
__global__ __launch_bounds__(256) void cvt_all_kernel(
    const float* __restrict__ Q, const float* __restrict__ Wq,
    const float* __restrict__ Wo, const float* __restrict__ V,
    ushort* __restrict__ Qh, ushort* __restrict__ Ql,
    ushort* __restrict__ Wqh,
    ushort* __restrict__ Woh,
    ushort* __restrict__ Vth)
{
    __shared__ float tile[64][65];
    const int bid = blockIdx.x;
    const int t = threadIdx.x;
    if (bid < 3584) {
        if (bid < 512) {
            int idx = bid*256 + t;
            float4 v = ((const float4*)Q)[idx];
            ushort4 hh, ll;
            split2(v.x, hh.x, ll.x); split2(v.y, hh.y, ll.y);
            split2(v.z, hh.z, ll.z); split2(v.w, hh.w, ll.w);
            ((ushort4*)Qh)[idx] = hh;
            ((ushort4*)Ql)[idx] = ll;
        } else {
            const float* src; ushort* h; int idx;
            if (bid < 1536) { src = Wq; h = Wqh; idx = (bid-512)*256 + t; }
            else            { src = Wo; h = Woh; idx = (bid-1536)*256 + t; }
            float4 v = ((const float4*)src)[idx];
            ushort4 hh;
            hh.x = bf16_rne(v.x); hh.y = bf16_rne(v.y);
            hh.z = bf16_rne(v.z); hh.w = bf16_rne(v.w);
            ((ushort4*)h)[idx] = hh;
        }
        return;
    }
    const int vid = bid - 3584;
    const int v0 = (vid & 15) * 64;
    const int k0 = ((vid >> 4) & 7) * 64;
    const int b  = vid >> 7;
    const float* src = V + ((size_t)b*TK + k0)*VS + v0;
    #pragma unroll
    for (int p = 0; p < 4; ++p) {
        int r = (t >> 4) + p*16, c = (t & 15) * 4;
        float4 vv = *(const float4*)(src + (size_t)r*VS + c);
        tile[r][c] = vv.x; tile[r][c+1] = vv.y; tile[r][c+2] = vv.z; tile[r][c+3] = vv.w;
    }
    __syncthreads();
    ushort* dh = Vth + (size_t)b*(VS*TK) + (size_t)v0*TK + k0;
    #pragma unroll
    for (int p = 0; p < 4; ++p) {
        int vr = (t >> 4) + p*16, kc = (t & 15) * 4;
        ushort4 hh;
        hh.x = bf16_rne(tile[kc+0][vr]);
        hh.y = bf16_rne(tile[kc+1][vr]);
        hh.z = bf16_rne(tile[kc+2][vr]);
        hh.w = bf16_rne(tile[kc+3][vr]);
        *(ushort4*)(dh + (size_t)vr*TK + kc) = hh;
    }
}

// ---------------------------------------------------------------------------
// [2] 2-MFMA NT GEMM (A hi/lo, B hi only), M=512. A-GEMM. K-split 4.
// ---------------------------------------------------------------------------
__global__ __launch_bounds__(256) void mfma_nt2_kernel(
    const ushort* __restrict__ Ah, const ushort* __restrict__ Al,
    const ushort* __restrict__ Bh,
    float* __restrict__ Cp, int lda, int ldb, int Nout, int kchunk, int bstride)
{
    __shared__ alignas(16) ushort lA[2][64][40];
    __shared__ alignas(16) ushort lB[64][40];
    const int t = threadIdx.x;
    const int m0 = blockIdx.y * 64, n0 = blockIdx.x * 64, kz = blockIdx.z;
    const int k0 = kz * kchunk;
    const int batch = m0 >> 7;
    const ushort* bhp = Bh + (size_t)batch * bstride;
    const int srow = t >> 2, skc = (t & 3) * 8;
    const int lane = t & 63, w = t >> 6;
    const int wm = (w >> 1) * 32, wn = (w & 1) * 32;
    const int fr = lane & 15, fg = (lane >> 4) * 8;

    f32x4 acc00 = {0,0,0,0}, acc01 = {0,0,0,0}, acc10 = {0,0,0,0}, acc11 = {0,0,0,0};

    for (int kb = k0; kb < k0 + kchunk; kb += 32) {
        *(uint4*)&lA[0][srow][skc] = *(const uint4*)(Ah  + (size_t)(m0+srow)*lda + kb + skc);
        *(uint4*)&lA[1][srow][skc] = *(const uint4*)(Al  + (size_t)(m0+srow)*lda + kb + skc);
        *(uint4*)&lB[srow][skc]    = *(const uint4*)(bhp + (size_t)(n0+srow)*ldb + kb + skc);
        __syncthreads();
        bf16x8 ah0 = *(const bf16x8*)&lA[0][wm + fr     ][fg];
        bf16x8 ah1 = *(const bf16x8*)&lA[0][wm + 16 + fr][fg];
        bf16x8 al0 = *(const bf16x8*)&lA[1][wm + fr     ][fg];
        bf16x8 al1 = *(const bf16x8*)&lA[1][wm + 16 + fr][fg];
        bf16x8 bh0 = *(const bf16x8*)&lB[wn + fr     ][fg];
        bf16x8 bh1 = *(const bf16x8*)&lB[wn + 16 + fr][fg];
        acc00 = MFMA16(ah0, bh0, acc00);
        acc00 = MFMA16(al0, bh0, acc00);
        acc01 = MFMA16(ah0, bh1, acc01);
        acc01 = MFMA16(al0, bh1, acc01);
        acc10 = MFMA16(ah1, bh0, acc10);
        acc10 = MFMA16(al1, bh0, acc10);
        acc11 = MFMA16(ah1, bh1, acc11);
        acc11 = MFMA16(al1, bh1, acc11);
        __syncthreads();
    }
    float* o = Cp + (size_t)kz * 512 * Nout;
    const int orow = (lane >> 4) * 4;
    #pragma unroll
    for (int r2 = 0; r2 < 4; ++r2) {
        o[(size_t)(m0+wm+orow+r2)*Nout      + n0+wn+fr]      = acc00[r2];
        o[(size_t)(m0+wm+orow+r2)*Nout      + n0+wn+16+fr]   = acc01[r2];
        o[(size_t)(m0+wm+16+orow+r2)*Nout   + n0+wn+fr]      = acc10[r2];
        o[(size_t)(m0+wm+16+orow+r2)*Nout   + n0+wn+16+fr]   = acc11[r2];
    }
}

// ---------------------------------------------------------------------------
// [6] 1-MFMA plain-bf16 NT GEMM (A hi, B hi), M=512. PV. K-split 4.
// ---------------------------------------------------------------------------
__global__ __launch_bounds__(256) void mfma_nt1_kernel(
    const ushort* __restrict__ Ah,
    const ushort* __restrict__ Bh,
    float* __restrict__ Cp, int lda, int ldb, int Nout, int kchunk, int bstride)
{
    __shared__ alignas(16) ushort lA[64][40];
    __shared__ alignas(16) ushort lB[64][40];
    const int t = threadIdx.x;
    const int m0 = blockIdx.y * 64, n0 = blockIdx.x * 64, kz = blockIdx.z;
    const int k0 = kz * kchunk;
    const int batch = m0 >> 7;
    const ushort* bhp = Bh + (size_t)batch * bstride;
    const int srow = t >> 2, skc = (t & 3) * 8;
    const int lane = t & 63, w = t >> 6;
    const int wm = (w >> 1) * 32, wn = (w & 1) * 32;
    const int fr = lane & 15, fg = (lane >> 4) * 8;

    f32x4 acc00 = {0,0,0,0}, acc01 = {0,0,0,0}, acc10 = {0,0,0,0}, acc11 = {0,0,0,0};

    for (int kb = k0; kb < k0 + kchunk; kb += 32) {
        *(uint4*)&lA[srow][skc] = *(const uint4*)(Ah  + (size_t)(m0+srow)*lda + kb + skc);
        *(uint4*)&lB[srow][skc] = *(const uint4*)(bhp + (size_t)(n0+srow)*ldb + kb + skc);
        __syncthreads();
        bf16x8 ah0 = *(const bf16x8*)&lA[wm + fr     ][fg];
        bf16x8 ah1 = *(const bf16x8*)&lA[wm + 16 + fr][fg];
        bf16x8 bh0 = *(const bf16x8*)&lB[wn + fr     ][fg];
        bf16x8 bh1 = *(const bf16x8*)&lB[wn + 16 + fr][fg];
        acc00 = MFMA16(ah0, bh0, acc00);
        acc01 = MFMA16(ah0, bh1, acc01);
        acc10 = MFMA16(ah1, bh0, acc10);
        acc11 = MFMA16(ah1, bh1, acc11);
        __syncthreads();
    }
    float* o = Cp + (size_t)kz * 512 * Nout;
    const int orow = (lane >> 4) * 4;
    #pragma unroll
    for (int r2 = 0; r2 < 4; ++r2) {
        o[(size_t)(m0+wm+orow+r2)*Nout      + n0+wn+fr]      = acc00[r2];
        o[(size_t)(m0+wm+orow+r2)*Nout      + n0+wn+16+fr]   = acc01[r2];
        o[(size_t)(m0+wm+16+orow+r2)*Nout   + n0+wn+fr]      = acc10[r2];
        o[(size_t)(m0+wm+16+orow+r2)*Nout   + n0+wn+16+fr]   = acc11[r2];
    }
}

// ---------------------------------------------------------------------------
// [3] Ea = exp2((sum of 4 Ap slices + bq) * K2F)
// ---------------------------------------------------------------------------
__global__ __launch_bounds__(256) void exp_combine_kernel(
    const float* __restrict__ Ap, const float* __restrict__ bias,
    float* __restrict__ E)
{
    int i = blockIdx.x * 256 + threadIdx.x;
    float4 p0 = ((const float4*)Ap)[i];
    float4 p1 = ((const float4*)(Ap + SLICE))[i];
    float4 p2 = ((const float4*)(Ap + 2*SLICE))[i];
    float4 p3 = ((const float4*)(Ap + 3*SLICE))[i];
    float4 bb = ((const float4*)bias)[i & 255];
    float4 r;
    r.x = exp2f((p0.x+p1.x+p2.x+p3.x+bb.x) * K2F);
    r.y = exp2f((p0.y+p1.y+p2.y+p3.y+bb.y) * K2F);
    r.z = exp2f((p0.z+p1.z+p2.z+p3.z+bb.z) * K2F);
    r.w = exp2f((p0.w+p1.w+p2.w+p3.w+bb.w) * K2F);
    ((float4*)E)[i] = r;
}

// ---------------------------------------------------------------------------
// [4] scores v13: 512-thread blocks, 64q x 64k x 128n (two 64-n halves,
// register-prefetched), 2x4/thread, QUAD-rcp. ea row-major [q][n] (b128
// broadcast reads + b128 staged writes); ek [n][k]. Grid 8x8x8 = 512 blocks.
// ---------------------------------------------------------------------------
__global__ __launch_bounds__(512, 4) void score_v13_kernel(
    const float* __restrict__ Ea,   // [512][1024]
    const float* __restrict__ keys,
    const float* __restrict__ watt,
    float* __restrict__ Sp)         // [8][512][512]
{
    __shared__ float ea[64][68];    // [q][n]
    __shared__ float ek[64][68];    // [n][k]
    __shared__ float wl[64];
    const int tid = threadIdx.x;
    const int kt = blockIdx.x;      // 0..7
    const int qt = blockIdx.y;      // 0..7
    const int nh = blockIdx.z;      // 0..7
    const int q0 = qt * 64;
    const int b  = qt >> 1;
    const int k0 = b*TK + kt*64;
    const int tx = tid & 15;
    const int ty = tid >> 4;
    const int sq  = tid >> 3;       // staging row (q for ea, k for ek)
    const int snc = (tid & 7) * 8;  // staging n offset
    float acc[2][4] = {};

    // prefetch registers (half operands)
    float4 rE0, rE1, rK0, rK1;
    float  rW = 0.f;
    {   // load half 0
        const int nbeg = nh*128;
        const float* ep = Ea + (size_t)(q0 + sq)*NN + nbeg + snc;
        rE0 = *(const float4*)(ep);
        rE1 = *(const float4*)(ep + 4);
        const float* kp = keys + (size_t)(k0 + sq)*NN + nbeg + snc;
        rK0 = *(const float4*)(kp);
        rK1 = *(const float4*)(kp + 4);
        if (tid < 64) rW = watt[nbeg + tid];
    }

    #pragma unroll
    for (int half = 0; half < 2; ++half) {
        if (half) __syncthreads();          // all waves done with prev LDS
        // stage regs -> LDS
        *(float4*)&ea[sq][snc]     = rE0;
        *(float4*)&ea[sq][snc + 4] = rE1;
        ek[snc+0][sq] = exp2f(rK0.x * K2F);
        ek[snc+1][sq] = exp2f(rK0.y * K2F);
        ek[snc+2][sq] = exp2f(rK0.z * K2F);
        ek[snc+3][sq] = exp2f(rK0.w * K2F);
        ek[snc+4][sq] = exp2f(rK1.x * K2F);
        ek[snc+5][sq] = exp2f(rK1.y * K2F);
        ek[snc+6][sq] = exp2f(rK1.z * K2F);
        ek[snc+7][sq] = exp2f(rK1.w * K2F);
        if (tid < 64) wl[tid] = rW;
        __syncthreads();

        if (half == 0) {   // issue next-half loads; land during compute
            const int nbeg = nh*128 + 64;
            const float* ep = Ea + (size_t)(q0 + sq)*NN + nbeg + snc;
            rE0 = *(const float4*)(ep);
            rE1 = *(const float4*)(ep + 4);
            const float* kp = keys + (size_t)(k0 + sq)*NN + nbeg + snc;
            rK0 = *(const float4*)(kp);
            rK1 = *(const float4*)(kp + 4);
            if (tid < 64) rW = watt[nbeg + tid];
        }

        #pragma unroll 4
        for (int g = 0; g < 16; ++g) {
            float4 a0 = *(const float4*)&ea[ty*2 + 0][4*g];   // (E0,E1,E2,E3) for q-row 0
            float4 a1 = *(const float4*)&ea[ty*2 + 1][4*g];   // ... for q-row 1
            float4 f0 = *(const float4*)&ek[4*g+0][tx*4];
            float4 f1 = *(const float4*)&ek[4*g+1][tx*4];
            float4 f2 = *(const float4*)&ek[4*g+2][tx*4];
            float4 f3 = *(const float4*)&ek[4*g+3][tx*4];
            float4 w4 = *(const float4*)&wl[4*g];
            float F0[4] = {f0.x, f0.y, f0.z, f0.w};
            float F1[4] = {f1.x, f1.y, f1.z, f1.w};
            float F2[4] = {f2.x, f2.y, f2.z, f2.w};
            float F3[4] = {f3.x, f3.y, f3.z, f3.w};
            #pragma unroll
            for (int i = 0; i < 2; ++i) {
                const float4 a = i ? a1 : a0;
                #pragma unroll
                for (int j = 0; j < 4; ++j) {
                    float A  = fmaf(a.x, F0[j], 1.0f);
                    float Bv = fmaf(a.y, F1[j], 1.0f);
                    float C  = fmaf(a.z, F2[j], 1.0f);
                    float D  = fmaf(a.w, F3[j], 1.0f);
                    float AB = A * Bv;
                    float CD = C * D;
                    float n01 = fmaf(w4.x, Bv, w4.y * A);
                    float n23 = fmaf(w4.z, D,  w4.w * C);
                    float num = fmaf(n01, CD, n23 * AB);
                    acc[i][j] = fmaf(num, __builtin_amdgcn_rcpf(AB * CD), acc[i][j]);
                }
            }
        }
    }
    float* o = Sp + ((size_t)nh*512 + q0 + ty*2)*TK + kt*64 + tx*4;
    #pragma unroll
    for (int i = 0; i < 2; ++i) {
        float4 r = {-2.0f*acc[i][0], -2.0f*acc[i][1], -2.0f*acc[i][2], -2.0f*acc[i][3]};
        *(float4*)(o + (size_t)i*TK) = r;
    }
}

// ---------------------------------------------------------------------------
// [5] softmax over k of sum_{h<8} Sp[h]; P f32 (output 1) + Ph (bf16)
// ---------------------------------------------------------------------------
__global__ __launch_bounds__(256) void softmax_kernel(
    const float* __restrict__ Sp, float* __restrict__ P,
    ushort* __restrict__ Ph)
{
    const int lane = threadIdx.x & 63;
    const int wid  = threadIdx.x >> 6;
    const int row  = blockIdx.x * 4 + wid;
    const size_t S = (size_t)512*512;
    float v[8];
    float m = -3.4e38f;
    #pragma unroll
    for (int j = 0; j < 8; ++j) {
        int k = lane + j*64;
        float s = 0.f;
        #pragma unroll
        for (int h = 0; h < 8; ++h)
            s += Sp[h*S + (size_t)row*TK + k];
        v[j] = s;
        m = fmaxf(m, v[j]);
    }
    #pragma unroll
    for (int off = 32; off; off >>= 1) m = fmaxf(m, __shfl_xor(m, off, 64));
    float sum = 0.f;
    #pragma unroll
    for (int j = 0; j < 8; ++j) { v[j] = exp2f((v[j] - m) * LOG2EF); sum += v[j]; }
    #pragma unroll
    for (int off = 32; off; off >>= 1) sum += __shfl_xor(sum, off, 64);
    float inv = 1.0f / sum;
    #pragma unroll
    for (int j = 0; j < 8; ++j) {
        int k = lane + j*64;
        float pv = v[j] * inv;
        P[(size_t)row * TK + k] = pv;
        Ph[(size_t)row * TK + k] = bf16_rne(pv);
    }
}

// ---------------------------------------------------------------------------
// [7] Cx = sum of 4 Ep slices -> hi bf16 only
// ---------------------------------------------------------------------------
__global__ __launch_bounds__(256) void combine_cvt_kernel(
    const float* __restrict__ Ep, ushort* __restrict__ Ch)
{
    int i = blockIdx.x * 256 + threadIdx.x;
    float4 p0 = ((const float4*)Ep)[i];
    float4 p1 = ((const float4*)(Ep + SLICE))[i];
    float4 p2 = ((const float4*)(Ep + 2*SLICE))[i];
    float4 p3 = ((const float4*)(Ep + 3*SLICE))[i];
    float4 s = {p0.x+p1.x+p2.x+p3.x, p0.y+p1.y+p2.y+p3.y,
                p0.z+p1.z+p2.z+p3.z, p0.w+p1.w+p2.w+p3.w};
    ushort4 hh;
    hh.x = bf16_rne(s.x); hh.y = bf16_rne(s.y);
    hh.z = bf16_rne(s.z); hh.w = bf16_rne(s.w);
    ((ushort4*)Ch)[i] = hh;
}

// ---------------------------------------------------------------------------
// [8] out-GEMM: A = [Qh | Cxh] (hi only), B = Woh (1-MFMA). K=2048/4.
// ---------------------------------------------------------------------------
__global__ __launch_bounds__(256) void mfma_out_kernel(
    const ushort* __restrict__ Qh,
    const ushort* __restrict__ Cxh,
    const ushort* __restrict__ Wh,  // [1024][2048] hi
    float* __restrict__ Fp)
{
    __shared__ alignas(16) ushort lA[64][40];
    __shared__ alignas(16) ushort lB[64][40];
    const int t = threadIdx.x;
    const int m0 = blockIdx.y * 64, n0 = blockIdx.x * 64, kz = blockIdx.z;
    const ushort* ah_p = (kz < 2) ? Qh : Cxh;
    const int akoff = (kz & 1) * 512;
    const int bkoff = kz * 512;
    const int srow = t >> 2, skc = (t & 3) * 8;
    const int lane = t & 63, w = t >> 6;
    const int wm = (w >> 1) * 32, wn = (w & 1) * 32;
    const int fr = lane & 15, fg = (lane >> 4) * 8;

    f32x4 acc00 = {0,0,0,0}, acc01 = {0,0,0,0}, acc10 = {0,0,0,0}, acc11 = {0,0,0,0};

    for (int kk = 0; kk < 512; kk += 32) {
        size_t aoff = (size_t)(m0+srow)*1024 + akoff + kk + skc;
        *(uint4*)&lA[srow][skc] = *(const uint4*)(ah_p + aoff);
        *(uint4*)&lB[srow][skc] =
            *(const uint4*)(Wh + (size_t)(n0+srow)*2048 + bkoff + kk + skc);
        __syncthreads();
        bf16x8 ah0 = *(const bf16x8*)&lA[wm + fr     ][fg];
        bf16x8 ah1 = *(const bf16x8*)&lA[wm + 16 + fr][fg];
        bf16x8 bh0 = *(const bf16x8*)&lB[wn + fr     ][fg];
        bf16x8 bh1 = *(const bf16x8*)&lB[wn + 16 + fr][fg];
        acc00 = MFMA16(ah0, bh0, acc00);
        acc01 = MFMA16(ah0, bh1, acc01);
        acc10 = MFMA16(ah1, bh0, acc10);
        acc11 = MFMA16(ah1, bh1, acc11);
        __syncthreads();
    }
    float* o = Fp + (size_t)kz * SLICE;
    const int orow = (lane >> 4) * 4;
    #pragma unroll
    for (int r2 = 0; r2 < 4; ++r2) {
        o[(size_t)(m0+wm+orow+r2)*1024    + n0+wn+fr]    = acc00[r2];
        o[(size_t)(m0+wm+orow+r2)*1024    + n0+wn+16+fr] = acc01[r2];
        o[(size_t)(m0+wm+16+orow+r2)*1024 + n0+wn+fr]    = acc10[r2];
        o[(size_t)(m0+wm+16+orow+r2)*1024 + n0+wn+16+fr] = acc11[r2];
    }
}

// ---------------------------------------------------------------------------
// [9] out = tanh(sum Fp + bias)
// ---------------------------------------------------------------------------
__global__ __launch_bounds__(256) void tanh_combine_kernel(
    const float* __restrict__ Fp, const float* __restrict__ bias,
    float* __restrict__ out)
{
    int i = blockIdx.x * 256 + threadIdx.x;
    const size_t S = (size_t)B_*TQ*OS;
    float4 p0 = ((const float4*)Fp)[i];
    float4 p1 = ((const float4*)(Fp + S))[i];
    float4 p2 = ((const float4*)(Fp + 2*S))[i];
    float4 p3 = ((const float4*)(Fp + 3*S))[i];
    float4 bb = ((const float4*)bias)[i & 255];
    float4 r;
    r.x = tanhf(p0.x + p1.x + p2.x + p3.x + bb.x);
    r.y = tanhf(p0.y + p1.y + p2.y + p3.y + bb.y);
    r.z = tanhf(p0.z + p1.z + p2.z + p3.z + bb.z);
    r.w = tanhf(p0.w + p1.w + p2.w + p3.w + bb.w);
    ((float4*)out)[i] = r;
}

// ---------------------------------------------------------------------------
extern "C" void kernel_launch(void* const* d_in, const int* in_sizes, int n_in,
                              void* d_out, int out_size, void* d_ws, size_t ws_size,
                              hipStream_t stream)
{
    const float* query  = (const float*)d_in[0];
    const float* keys   = (const float*)d_in[1];
    const float* values = (const float*)d_in[2];
    const float* Wq     = (const float*)d_in[3];
    const float* bq     = (const float*)d_in[4];
    const float* watt   = (const float*)d_in[5];
    // d_in[6] = b_att: dropped (softmax shift-invariance)
    const float* Wout   = (const float*)d_in[7];
    const float* bout   = (const float*)d_in[8];

    float* out = (float*)d_out;                    // output 0 (524288 f32)
    float* P   = out + (size_t)B_*TQ*OS;           // output 1 (262144 f32)

    char* base = (char*)d_ws;
    const size_t MB = 1u << 20;
    ushort* Qh  = (ushort*)(base +  0*MB);
    ushort* Ql  = (ushort*)(base +  1*MB);
    ushort* Wqh = (ushort*)(base +  2*MB);   // 2 MB (hi only)
    ushort* Woh = (ushort*)(base +  6*MB);   // 4 MB (hi only)
    ushort* Vth = (ushort*)(base + 10*MB);   // 4 MB (hi only)
    float*  Ap  = (float*) (base + 14*MB);   // [4][512][1024] = 8 MB
    float*  Ea  = (float*) (base + 22*MB);   // 2 MB
    float*  Sp  = (float*) (base + 24*MB);   // [8][512][512] = 8 MB
    ushort* Ph  = (ushort*)(base + 32*MB);   // 0.5 MB (hi only)
    float*  Ep  = (float*) (base + 33*MB);   // [4][512][1024] = 8 MB
    ushort* Cxh = (ushort*)(base + 41*MB);   // 1 MB (hi only)
    float*  Fp  = (float*) (base + 43*MB);   // [4][512][1024] = 8 MB

    // [1] conversions + V transpose (Wq/Wout/V hi-only; Q hi/lo)
    cvt_all_kernel<<<dim3(4096), dim3(256), 0, stream>>>(
        query, Wq, Wout, values, Qh, Ql, Wqh, Woh, Vth);
    // [2] A-GEMM partials: Q @ Wq^T (2-MFMA, A hi/lo; K=1024 split 4)
    mfma_nt2_kernel<<<dim3(16, 8, 4), dim3(256), 0, stream>>>(
        Qh, Ql, Wqh, Ap, 1024, 1024, 1024, 256, 0);
    // [3] Ea = exp(2*(sum Ap + bq))
    exp_combine_kernel<<<dim3(512), dim3(256), 0, stream>>>(Ap, bq, Ea);
    // [4] scores v13 (quad-rcp, row-major ea, register prefetch)
    score_v13_kernel<<<dim3(8, 8, 8), dim3(512), 0, stream>>>(Ea, keys, watt, Sp);
    // [5] softmax -> P (output 1) + Ph (bf16 hi)
    softmax_kernel<<<dim3(128), dim3(256), 0, stream>>>(Sp, P, Ph);
    // [6] PV partials: P @ V (1-MFMA bf16, per-batch, K=512 split 4)
    mfma_nt1_kernel<<<dim3(16, 8, 4), dim3(256), 0, stream>>>(
        Ph, Vth, Ep, 512, 512, 1024, 128, VS*TK);
    // [7] Cx = sum Ep -> hi bf16
    combine_cvt_kernel<<<dim3(512), dim3(256), 0, stream>>>(Ep, Cxh);
    // [8] out-GEMM partials (1-MFMA bf16; K=2048 split 4)
    mfma_out_kernel<<<dim3(16, 8, 4), dim3(256), 0, stream>>>(
        Qh, Cxh, Woh, Fp);
    // [9] out = tanh(sum + bout)
    tanh_combine_kernel<<<dim3(512), dim3(256), 0, stream>>>(Fp, bout, out);
}